// Round 6
// baseline (13012.189 us; speedup 1.0000x reference)
//
#include <hip/hip_runtime.h>
#include <math.h>

// ---------------------------------------------------------------------------
// AnticipatoryRestaurantGNN round 6:
//  - k_attn: 2 nodes per wave (2x memory-level parallelism + ILP on the
//    serial softmax chain), edge-attr via 4B gather + bpermute (no LDS
//    staging), shared We epilogue for the node pair
//  - Q and S buffers in bf16 (less write + gather traffic)
//  - k_head computes per-graph counts inline (one less launch)
// ---------------------------------------------------------------------------

#define EPS 1e-5f
typedef unsigned short ushort_t;
typedef unsigned int uint_t;

using f32x4 = __attribute__((ext_vector_type(4))) float;
using s16x8 = __attribute__((ext_vector_type(8))) short;
using u16x8 = __attribute__((ext_vector_type(8))) unsigned short;

__device__ __forceinline__ ushort_t f2bf(float f) {
  union { float f; uint_t u; } v; v.f = f;
  uint_t u = v.u;
  uint_t r = (u + 0x7FFFu + ((u >> 16) & 1u)) >> 16;   // RNE
  return (ushort_t)r;
}
__device__ __forceinline__ float bf2f(ushort_t h) {
  union { uint_t u; float f; } v; v.u = ((uint_t)h) << 16;
  return v.f;
}

__device__ __forceinline__ void gl_lds16(const void* g, void* l) {
  __builtin_amdgcn_global_load_lds(
      (const __attribute__((address_space(1))) void*)g,
      (__attribute__((address_space(3))) void*)l, 16, 0, 0);
}

__device__ __forceinline__ float red16(float x) {
  x += __shfl_xor(x, 1, 64);
  x += __shfl_xor(x, 2, 64);
  x += __shfl_xor(x, 4, 64);
  x += __shfl_xor(x, 8, 64);
  return x;
}

// ---------------- CSR build (by dst; dst reused across all 4 layers) -------
__global__ void k_count(const int* __restrict__ dst, int* __restrict__ deg, int n) {
  int i = blockIdx.x * 256 + threadIdx.x;
  if (i < n) atomicAdd(&deg[dst[i]], 1);
}

__global__ void k_scan(const int* __restrict__ deg, int* __restrict__ row_ptr, int n) {
  __shared__ int wsum[16];
  __shared__ int carry_s;
  int t = threadIdx.x, lane = t & 63, w = t >> 6;
  if (t == 0) { carry_s = 0; row_ptr[0] = 0; }
  __syncthreads();
  for (int base = 0; base < n; base += 1024) {
    int v = (base + t < n) ? deg[base + t] : 0;
    int x = v;
#pragma unroll
    for (int off = 1; off < 64; off <<= 1) {
      int y = __shfl_up(x, off, 64);
      if (lane >= off) x += y;
    }
    if (lane == 63) wsum[w] = x;
    __syncthreads();
    if (w == 0 && lane < 16) {
      int s = wsum[lane];
#pragma unroll
      for (int off = 1; off < 16; off <<= 1) {
        int y = __shfl_up(s, off, 64);
        if (lane >= off) s += y;
      }
      wsum[lane] = s;
    }
    __syncthreads();
    int add = (w > 0) ? wsum[w - 1] : 0;
    int incl = x + add + carry_s;
    if (base + t < n) row_ptr[base + t + 1] = incl;
    __syncthreads();
    if (t == 1023) carry_s = incl;
    __syncthreads();
  }
}

__global__ void k_scatter(const int* __restrict__ dst, const int* __restrict__ row_ptr,
                          int* __restrict__ fill, int* __restrict__ csr, int n) {
  int i = blockIdx.x * 256 + threadIdx.x;
  if (i < n) {
    int d = dst[i];
    int pos = atomicAdd(&fill[d], 1);
    csr[row_ptr[d] + pos] = i;
  }
}

// ---------------- weight convert: Wcat_t[l][n=1152][k=256] bf16 ------------
__global__ void k_wconv(const float* __restrict__ Wq, const float* __restrict__ Wk,
                        const float* __restrict__ Wv, const float* __restrict__ Ws,
                        ushort_t* __restrict__ Wcat_t) {
  __shared__ float tile[32][33];
  int l = blockIdx.z >> 2, sel = blockIdx.z & 3;
  const float* W = (sel == 0) ? Wq : (sel == 1) ? Wk : (sel == 2) ? Wv : Ws;
  W += (size_t)l * 65536;
  int k0 = blockIdx.x * 32, n0 = blockIdx.y * 32;
  int tx = threadIdx.x, ty = threadIdx.y;           // 32 x 8
#pragma unroll
  for (int i = 0; i < 32; i += 8) tile[ty + i][tx] = W[(size_t)(k0 + ty + i) * 256 + n0 + tx];
  __syncthreads();
  ushort_t* dst = Wcat_t + (size_t)l * (1152 * 256) + (size_t)(sel * 256 + n0) * 256 + k0;
#pragma unroll
  for (int i = 0; i < 32; i += 8) dst[(size_t)(ty + i) * 256 + tx] = f2bf(tile[tx][ty + i]);
}

// composite rows 1024..1091: M[ci][j] = sum_{c in head(j)} Wq[ci][c]*w2[c]
__global__ void k_mkdq(const float* __restrict__ Wq, const float* __restrict__ bq,
                       const float* __restrict__ We, const float* __restrict__ be,
                       ushort_t* __restrict__ Wcat_t, float* __restrict__ bias_cat) {
  int j = blockIdx.x;        // 0..67
  int l = blockIdx.y;        // 0..3
  int ci = threadIdx.x;      // 0..255
  __shared__ float w2[64];
  int h = (j < 64) ? (j >> 4) : (j - 64);
  if (ci < 64) {
    float v;
    if (j < 64) v = We[(size_t)l * 4096 + (j & 15) * 256 + h * 64 + ci];
    else        v = be[l * 256 + h * 64 + ci];
    w2[ci] = v * 0.125f;
  }
  __syncthreads();
  const float* Wq_l = Wq + (size_t)l * 65536;
  float acc = 0.f;
#pragma unroll 8
  for (int c = 0; c < 64; ++c) acc += Wq_l[(size_t)ci * 256 + h * 64 + c] * w2[c];
  Wcat_t[(size_t)l * (1152 * 256) + (size_t)(1024 + j) * 256 + ci] = f2bf(acc);
  if (ci == 0) {
    const float* bq_l = bq + l * 256;
    float d0 = 0.f;
    for (int c = 0; c < 64; ++c) d0 += bq_l[h * 64 + c] * w2[c];
    bias_cat[l * 1152 + 1024 + j] = d0;
  }
}

__global__ void k_bconv(const float* __restrict__ bq, const float* __restrict__ bk,
                        const float* __restrict__ bv, const float* __restrict__ bs,
                        float* __restrict__ bias_cat) {
  int idx = blockIdx.x * 256 + threadIdx.x;   // 4096 total
  if (idx >= 4096) return;
  int l = idx >> 10, rest = idx & 1023, sel = rest >> 8, c = rest & 255;
  const float* p = (sel == 0) ? bq : (sel == 1) ? bk : (sel == 2) ? bv : bs;
  bias_cat[l * 1152 + rest] = p[l * 256 + c];
}

// ---------------- fp32 tiled GEMM (input projection only) ------------------
#define BM 128
#define BN 64
#define BK 16
__global__ __launch_bounds__(256) void k_gemm(
    const float* __restrict__ A, const float* __restrict__ B,
    const float* __restrict__ bias, float* __restrict__ C,
    ushort_t* __restrict__ C16, int M, int Kd, int Nd) {
  __shared__ float As[BK][BM + 4];
  __shared__ float Bs[BK][BN + 4];
  int t = threadIdx.x;
  int tx = t & 15, ty = t >> 4;
  int row0 = blockIdx.y * BM, col0 = blockIdx.x * BN;
  float acc[8][4] = {};
  for (int k0 = 0; k0 < Kd; k0 += BK) {
#pragma unroll
    for (int i = 0; i < 2; ++i) {
      int idx = t + i * 256;
      int r = idx >> 2, kk = (idx & 3) * 4;
      float4 a = make_float4(0.f, 0.f, 0.f, 0.f);
      if (row0 + r < M) a = *(const float4*)(A + (size_t)(row0 + r) * Kd + k0 + kk);
      As[kk + 0][r] = a.x; As[kk + 1][r] = a.y; As[kk + 2][r] = a.z; As[kk + 3][r] = a.w;
    }
    {
      int kk = t >> 4, cc = (t & 15) * 4;
      float4 b = *(const float4*)(B + (size_t)(k0 + kk) * Nd + col0 + cc);
      Bs[kk][cc] = b.x; Bs[kk][cc + 1] = b.y; Bs[kk][cc + 2] = b.z; Bs[kk][cc + 3] = b.w;
    }
    __syncthreads();
#pragma unroll
    for (int kk = 0; kk < BK; ++kk) {
      float ar[8], br[4];
#pragma unroll
      for (int i = 0; i < 8; ++i) ar[i] = As[kk][ty * 8 + i];
#pragma unroll
      for (int j = 0; j < 4; ++j) br[j] = Bs[kk][tx * 4 + j];
#pragma unroll
      for (int i = 0; i < 8; ++i)
#pragma unroll
        for (int j = 0; j < 4; ++j) acc[i][j] += ar[i] * br[j];
    }
    __syncthreads();
  }
#pragma unroll
  for (int i = 0; i < 8; ++i) {
    int r = row0 + ty * 8 + i;
    if (r < M) {
      int c = col0 + tx * 4;
      float4 o;
      o.x = acc[i][0] + bias[c + 0];
      o.y = acc[i][1] + bias[c + 1];
      o.z = acc[i][2] + bias[c + 2];
      o.w = acc[i][3] + bias[c + 3];
      *(float4*)(C + (size_t)r * Nd + c) = o;
      ushort4 h;
      h.x = f2bf(o.x); h.y = f2bf(o.y); h.z = f2bf(o.z); h.w = f2bf(o.w);
      *(ushort4*)(C16 + (size_t)r * Nd + c) = h;
    }
  }
}

// ---------------- fused QKVS+Dq bf16 MFMA GEMM -----------------------------
// C[M x 1152] = A[M x 256] @ Bt^T  (Bt is [1152][256], k-contiguous)
__global__ __launch_bounds__(256) void k_qkvs(
    const ushort_t* __restrict__ A, const ushort_t* __restrict__ Bt,
    const float* __restrict__ bias, ushort_t* __restrict__ Qb16,
    ushort_t* __restrict__ KVb, ushort_t* __restrict__ Sb16,
    float* __restrict__ Dqb, int M) {
  __shared__ short lds_a[8192];   // 128 x 64 bf16 (swizzled granules)
  __shared__ short lds_b[8192];
  int t = threadIdx.x;
  int lane = t & 63, wv = t >> 6;
  int row0 = blockIdx.y * 128, col0 = blockIdx.x * 128;

  f32x4 acc[4][4];
#pragma unroll
  for (int im = 0; im < 4; ++im)
#pragma unroll
    for (int in = 0; in < 4; ++in) acc[im][in] = (f32x4){0.f, 0.f, 0.f, 0.f};

  int ln16 = lane & 15, q = lane >> 4;
  int mbase = (wv >> 1) * 64;
  int nbase = (wv & 1) * 64;

  for (int kk = 0; kk < 4; ++kk) {
    int k0 = kk * 64;
    __syncthreads();          // protect previous iteration's LDS reads
#pragma unroll
    for (int i = 0; i < 4; ++i) {
      int gi = i * 256 + t;
      int r = gi >> 3, c = (gi & 7) ^ (r & 7);
      int gr = row0 + r; if (gr > M - 1) gr = M - 1;
      gl_lds16(A + (size_t)gr * 256 + k0 + c * 8, &((int4*)lds_a)[gi]);
      gl_lds16(Bt + (size_t)(col0 + r) * 256 + k0 + c * 8, &((int4*)lds_b)[gi]);
    }
    __syncthreads();          // drains vmcnt(0) then barrier
#pragma unroll
    for (int kc = 0; kc < 2; ++kc) {
      s16x8 af[4], bf[4];
      int cq = kc * 4 + q;
#pragma unroll
      for (int im = 0; im < 4; ++im) {
        int r = mbase + im * 16 + ln16;
        af[im] = ((const s16x8*)lds_a)[r * 8 + (cq ^ (r & 7))];
      }
#pragma unroll
      for (int in = 0; in < 4; ++in) {
        int r = nbase + in * 16 + ln16;
        bf[in] = ((const s16x8*)lds_b)[r * 8 + (cq ^ (r & 7))];
      }
#pragma unroll
      for (int im = 0; im < 4; ++im)
#pragma unroll
        for (int in = 0; in < 4; ++in)
          acc[im][in] = __builtin_amdgcn_mfma_f32_16x16x32_bf16(af[im], bf[in], acc[im][in], 0, 0, 0);
    }
  }

  // epilogue: C[m = q*4+j][n = ln16] per tile.
#pragma unroll
  for (int in = 0; in < 4; ++in) {
    int ncol = col0 + nbase + in * 16 + ln16;
    int lc = ncol & 255;
    float bz = bias[ncol];
#pragma unroll
    for (int im = 0; im < 4; ++im) {
#pragma unroll
      for (int j = 0; j < 4; ++j) {
        int mr = row0 + mbase + im * 16 + q * 4 + j;
        if (mr < M) {
          float v = acc[im][in][j] + bz;
          if (ncol < 256)       Qb16[(size_t)mr * 256 + lc] = f2bf(v);
          else if (ncol < 512)  KVb[(size_t)mr * 512 + (lc >> 2) * 8 + (lc & 3)] = f2bf(v);
          else if (ncol < 768)  KVb[(size_t)mr * 512 + (lc >> 2) * 8 + (lc & 3) + 4] = f2bf(v);
          else if (ncol < 1024) Sb16[(size_t)mr * 256 + lc] = f2bf(v);
          else { int j2 = ncol - 1024; if (j2 < 68) Dqb[(size_t)mr * 68 + j2] = v; }
        }
      }
    }
  }
}

// ---------------- attention + beta-gate blend: TWO nodes per wave ----------
// lane l: channels 4l..4l+3 (head h = l>>4, t16 = l&15).
// Per node: score_h = qs.K[s] + ea[t]*dq[t,h] (red16) + qbe_h.
// Edge attrs: per 4-edge group, lane (k,t16) holds component t16 of edge k
// (one 4B gather), distributed in-loop via bpermute shfl.  KV ping-pong
// prefetch per node; the two nodes' chains interleave for ILP + MLP.
__global__ __launch_bounds__(256) void k_attn(
    const ushort_t* __restrict__ Qp, const ushort_t* __restrict__ KVm,
    const float* __restrict__ Dqp,
    const float* __restrict__ ea_g, const int* __restrict__ srcA,
    const float* __restrict__ We_l, const float* __restrict__ be_l,
    const float* __restrict__ Wb, const int* __restrict__ row_ptr,
    const int* __restrict__ csr, const ushort_t* __restrict__ Sp,
    float* __restrict__ xout, int nNodes) {
  __shared__ float sWb[768];
  int t = threadIdx.x;
  sWb[t] = Wb[t];
  sWb[t + 256] = Wb[t + 256];
  sWb[t + 512] = Wb[t + 512];
  __syncthreads();
  int lane = t & 63;
  int t16 = lane & 15;
  int nA = blockIdx.x * 8 + (t >> 6) * 2;
  if (nA >= nNodes) return;
  int nB = nA + 1;
  bool hasB = nB < nNodes;

  float4 be4 = *(const float4*)(be_l + 4 * lane);

  ushort4 qhA = *(const ushort4*)(Qp + (size_t)nA * 256 + 4 * lane);
  float4 qsA = make_float4(bf2f(qhA.x) * 0.125f, bf2f(qhA.y) * 0.125f,
                           bf2f(qhA.z) * 0.125f, bf2f(qhA.w) * 0.125f);
  float dqA = Dqp[(size_t)nA * 68 + lane];
  float qbeA = Dqp[(size_t)nA * 68 + 64 + (lane >> 4)];
  int begA = row_ptr[nA], endA = row_ptr[nA + 1];

  float4 qsB = make_float4(0.f, 0.f, 0.f, 0.f);
  float dqB = 0.f, qbeB = 0.f;
  int begB = 0, endB = 0;
  if (hasB) {
    ushort4 qhB = *(const ushort4*)(Qp + (size_t)nB * 256 + 4 * lane);
    qsB = make_float4(bf2f(qhB.x) * 0.125f, bf2f(qhB.y) * 0.125f,
                      bf2f(qhB.z) * 0.125f, bf2f(qhB.w) * 0.125f);
    dqB = Dqp[(size_t)nB * 68 + lane];
    qbeB = Dqp[(size_t)nB * 68 + 64 + (lane >> 4)];
    begB = row_ptr[nB]; endB = row_ptr[nB + 1];
  }

  float mA = -INFINITY, dnA = 0.f, waA = 0.f;
  float mB = -INFINITY, dnB = 0.f, waB = 0.f;
  float4 acA = make_float4(0.f, 0.f, 0.f, 0.f);
  float4 acB = make_float4(0.f, 0.f, 0.f, 0.f);

  int baseA = begA, baseB = begB;
  while (baseA < endA || baseB < endB) {
    int cntA = (baseA < endA) ? min(64, endA - baseA) : 0;
    int cntB = (baseB < endB) ? min(64, endB - baseB) : 0;
    int eA = 0, sA = 0, eB = 0, sB = 0;
    if (lane < cntA) { eA = csr[baseA + lane]; sA = srcA[eA]; }
    if (lane < cntB) { eB = csr[baseB + lane]; sB = srcA[eB]; }

    u16x8 kvA[2][4], kvB[2][4];
    float eaA[2], eaB[2];

    auto ldnode = [&](u16x8 (&kv)[4], float& eaR, int sL_, int eL_, int cnt, int g4) {
      if (g4 >= cnt) return;
      int esel = g4 + (lane >> 4);
      int eid = __shfl(eL_, (esel < 64) ? esel : 63, 64);
      eaR = ea_g[(size_t)eid * 16 + t16];
#pragma unroll
      for (int jj = 0; jj < 4; ++jj) {
        if (g4 + jj < cnt) {
          int s = __shfl(sL_, g4 + jj, 64);
          kv[jj] = *(const u16x8*)(KVm + (size_t)s * 512 + lane * 8);
        }
      }
    };
    auto procg = [&](const u16x8 (&kv)[4], float eaR, int g4, int cnt,
                     float& m, float& dn, float& wa, float4& ac,
                     const float4& qs, float dqv, float qbe) {
#pragma unroll
      for (int jj = 0; jj < 4; ++jj) {
        if (g4 + jj < cnt) {
          float eat = __shfl(eaR, (jj << 4) | t16, 64);
          float part = qs.x * bf2f(kv[jj][0]) + qs.y * bf2f(kv[jj][1]) +
                       qs.z * bf2f(kv[jj][2]) + qs.w * bf2f(kv[jj][3]) + eat * dqv;
          float p = red16(part) + qbe;
          float mn = fmaxf(m, p);
          float scl = __expf(m - mn);   // -inf first time -> 0
          float w = __expf(p - mn);
          m = mn;
          dn = dn * scl + w;
          ac.x = ac.x * scl + w * bf2f(kv[jj][4]);
          ac.y = ac.y * scl + w * bf2f(kv[jj][5]);
          ac.z = ac.z * scl + w * bf2f(kv[jj][6]);
          ac.w = ac.w * scl + w * bf2f(kv[jj][7]);
          wa = wa * scl + w * eat;
        }
      }
    };

    ldnode(kvA[0], eaA[0], sA, eA, cntA, 0);
    ldnode(kvB[0], eaB[0], sB, eB, cntB, 0);
    int gmax = max(cntA, cntB);
    int pp = 0;
    for (int g4 = 0; g4 < gmax; g4 += 4) {
      ldnode(kvA[pp ^ 1], eaA[pp ^ 1], sA, eA, cntA, g4 + 4);
      procg(kvA[pp], eaA[pp], g4, cntA, mA, dnA, waA, acA, qsA, dqA, qbeA);
      ldnode(kvB[pp ^ 1], eaB[pp ^ 1], sB, eB, cntB, g4 + 4);
      procg(kvB[pp], eaB[pp], g4, cntB, mB, dnB, waB, acB, qsB, dqB, qbeB);
      pp ^= 1;
    }
    baseA += 64;
    baseB += 64;
  }

  // epilogue (shared We loads for the node pair)
  float4 oA = make_float4(0.f, 0.f, 0.f, 0.f);
  float4 oB = make_float4(0.f, 0.f, 0.f, 0.f);
  float waccA = 0.f, waccB = 0.f;
  if (endA > begA) {
    float inv = 1.0f / dnA;
    oA.x = acA.x * inv + be4.x; oA.y = acA.y * inv + be4.y;
    oA.z = acA.z * inv + be4.z; oA.w = acA.w * inv + be4.w;
    waccA = waA * inv;
  }
  if (hasB && endB > begB) {
    float inv = 1.0f / dnB;
    oB.x = acB.x * inv + be4.x; oB.y = acB.y * inv + be4.y;
    oB.z = acB.z * inv + be4.z; oB.w = acB.w * inv + be4.w;
    waccB = waB * inv;
  }
  int lanebase = lane & 48;
#pragma unroll
  for (int tt = 0; tt < 16; ++tt) {
    float4 w4 = *(const float4*)(We_l + tt * 256 + 4 * lane);
    float wvA = __shfl(waccA, lanebase + tt, 64);
    float wvB = __shfl(waccB, lanebase + tt, 64);
    oA.x += wvA * w4.x; oA.y += wvA * w4.y; oA.z += wvA * w4.z; oA.w += wvA * w4.w;
    oB.x += wvB * w4.x; oB.y += wvB * w4.y; oB.z += wvB * w4.z; oB.w += wvB * w4.w;
  }

  // fused beta-gate blend (node A, then node B)
  int c = 4 * lane;
#pragma unroll
  for (int which = 0; which < 2; ++which) {
    if (which == 1 && !hasB) break;
    int n = (which == 0) ? nA : nB;
    float4 o = (which == 0) ? oA : oB;
    ushort4 rh = *(const ushort4*)(Sp + (size_t)n * 256 + 4 * lane);
    float4 r = make_float4(bf2f(rh.x), bf2f(rh.y), bf2f(rh.z), bf2f(rh.w));
    float z = o.x * sWb[c] + o.y * sWb[c + 1] + o.z * sWb[c + 2] + o.w * sWb[c + 3]
            + r.x * sWb[256 + c] + r.y * sWb[257 + c] + r.z * sWb[258 + c] + r.w * sWb[259 + c]
            + (o.x - r.x) * sWb[512 + c] + (o.y - r.y) * sWb[513 + c]
            + (o.z - r.z) * sWb[514 + c] + (o.w - r.w) * sWb[515 + c];
#pragma unroll
    for (int off = 1; off < 64; off <<= 1) z += __shfl_xor(z, off, 64);
    float beta = 1.0f / (1.0f + __expf(-z));
    float4 xn;
    xn.x = beta * r.x + (1.f - beta) * o.x;
    xn.y = beta * r.y + (1.f - beta) * o.y;
    xn.z = beta * r.z + (1.f - beta) * o.z;
    xn.w = beta * r.w + (1.f - beta) * o.w;
    *(float4*)(xout + (size_t)n * 256 + 4 * lane) = xn;
  }
}

// ---------------- batchnorm ------------------------------------------------
__global__ void k_bnstats(const float* __restrict__ x, float* __restrict__ sums,
                          float* __restrict__ sums2, int nRows) {
  int c = threadIdx.x;
  int rpb = (nRows + gridDim.x - 1) / gridDim.x;
  int r0 = blockIdx.x * rpb;
  int r1 = min(nRows, r0 + rpb);
  float s = 0.f, s2 = 0.f;
  for (int r = r0; r < r1; ++r) {
    float v = x[(size_t)r * 256 + c];
    s += v;
    s2 += v * v;
  }
  atomicAdd(&sums[c], s);
  atomicAdd(&sums2[c], s2);
}

__global__ __launch_bounds__(256) void k_bnapply(
    float* __restrict__ x, ushort_t* __restrict__ x16,
    const float* __restrict__ sums, const float* __restrict__ sums2,
    const float* __restrict__ gamma, const float* __restrict__ betap, int nRows) {
  int total4 = nRows * 64;
  float invN = 1.0f / (float)nRows;
  for (int i4 = blockIdx.x * 256 + threadIdx.x; i4 < total4; i4 += gridDim.x * 256) {
    int c4 = (i4 & 63) * 4;
    float4 xv = *(const float4*)(x + (size_t)i4 * 4);
    float4 s = *(const float4*)(sums + c4);
    float4 s2 = *(const float4*)(sums2 + c4);
    float4 g = *(const float4*)(gamma + c4);
    float4 b = *(const float4*)(betap + c4);
    float mu0 = s.x * invN, mu1 = s.y * invN, mu2 = s.z * invN, mu3 = s.w * invN;
    float sc0 = rsqrtf(s2.x * invN - mu0 * mu0 + EPS) * g.x;
    float sc1 = rsqrtf(s2.y * invN - mu1 * mu1 + EPS) * g.y;
    float sc2 = rsqrtf(s2.z * invN - mu2 * mu2 + EPS) * g.z;
    float sc3 = rsqrtf(s2.w * invN - mu3 * mu3 + EPS) * g.w;
    float4 v;
    v.x = (xv.x - mu0) * sc0 + b.x;
    v.y = (xv.y - mu1) * sc1 + b.y;
    v.z = (xv.z - mu2) * sc2 + b.z;
    v.w = (xv.w - mu3) * sc3 + b.w;
    v.x = v.x >= 0.f ? v.x : 0.1f * v.x;
    v.y = v.y >= 0.f ? v.y : 0.1f * v.y;
    v.z = v.z >= 0.f ? v.z : 0.1f * v.z;
    v.w = v.w >= 0.f ? v.w : 0.1f * v.w;
    *(float4*)(x + (size_t)i4 * 4) = v;
    ushort4 h;
    h.x = f2bf(v.x); h.y = f2bf(v.y); h.z = f2bf(v.z); h.w = f2bf(v.w);
    *(ushort4*)(x16 + (size_t)i4 * 4) = h;
  }
}

// ---------------- pooling + head -------------------------------------------
__global__ void k_pool(const float* __restrict__ x, const int* __restrict__ batch,
                       float* __restrict__ pool, int nRows) {
  int c = threadIdx.x;
  int rpb = (nRows + gridDim.x - 1) / gridDim.x;
  int r0 = blockIdx.x * rpb;
  int r1 = min(nRows, r0 + rpb);
  float acc = 0.f;
  int gc = -1;
  for (int r = r0; r < r1; ++r) {
    int g = batch[r];
    if (g != gc) {
      if (gc >= 0) atomicAdd(&pool[gc * 256 + c], acc);
      acc = 0.f;
      gc = g;
    }
    acc += x[(size_t)r * 256 + c];
  }
  if (gc >= 0) atomicAdd(&pool[gc * 256 + c], acc);
}

// head with inline per-graph counts (batch sorted -> binary search)
__global__ void k_head(const float* __restrict__ pool, const int* __restrict__ batch,
                       const float* __restrict__ hW, const float* __restrict__ hb,
                       float* __restrict__ outp, int nRows) {
  int g = blockIdx.x, lane = threadIdx.x;
  int lo = 0, hi = nRows;
  while (lo < hi) { int mid = (lo + hi) >> 1; if (batch[mid] < g) lo = mid + 1; else hi = mid; }
  int lb = lo;
  lo = 0; hi = nRows;
  while (lo < hi) { int mid = (lo + hi) >> 1; if (batch[mid] < g + 1) lo = mid + 1; else hi = mid; }
  float cnt = fmaxf((float)(lo - lb), 1.0f);
  float z = 0.f;
#pragma unroll
  for (int i = 0; i < 4; ++i) {
    int c = lane + i * 64;
    float s = pool[g * 256 + c];
    z += (s / cnt) * hW[c] + s * hW[256 + c];
  }
#pragma unroll
  for (int off = 1; off < 64; off <<= 1) z += __shfl_xor(z, off, 64);
  if (lane == 0) outp[g] = z + hb[0];
}

// ---------------------------------------------------------------------------
extern "C" void kernel_launch(void* const* d_in, const int* in_sizes, int n_in,
                              void* d_out, int out_size, void* d_ws, size_t ws_size,
                              hipStream_t stream) {
  const float* node_features = (const float*)d_in[0];
  const int*   edge_index    = (const int*)d_in[1];
  const float* edge_attr     = (const float*)d_in[2];
  const int*   batch         = (const int*)d_in[3];
  const float* proj_W  = (const float*)d_in[4];
  const float* proj_b  = (const float*)d_in[5];
  const float* Wq      = (const float*)d_in[6];
  const float* bq      = (const float*)d_in[7];
  const float* Wk      = (const float*)d_in[8];
  const float* bk      = (const float*)d_in[9];
  const float* Wv      = (const float*)d_in[10];
  const float* bv      = (const float*)d_in[11];
  const float* We      = (const float*)d_in[12];
  const float* be      = (const float*)d_in[13];
  const float* Wskip   = (const float*)d_in[14];
  const float* bskip   = (const float*)d_in[15];
  const float* Wbeta   = (const float*)d_in[16];
  const float* bn_gamma= (const float*)d_in[17];
  const float* bn_beta = (const float*)d_in[18];
  const float* head_W  = (const float*)d_in[19];
  const float* head_b  = (const float*)d_in[20];
  float* out_dev = (float*)d_out;

  const int Nn = in_sizes[0] / 64;   // 50000
  const int Ee = in_sizes[1] / 2;    // 500000
  const int Gg = out_size;           // 64

  char* ws = (char*)d_ws;
  size_t off = 0;
  auto alloc = [&](size_t bytes) -> void* {
    void* p = ws + off;
    off += (bytes + 255) & ~(size_t)255;
    return p;
  };
  float*    xb     = (float*)alloc((size_t)Nn * 256 * 4);
  float*    Dqb    = (float*)alloc((size_t)Nn * 68 * 4);
  ushort_t* Qb16   = (ushort_t*)alloc((size_t)Nn * 256 * 2);
  ushort_t* Sb16   = (ushort_t*)alloc((size_t)Nn * 256 * 2);
  ushort_t* KVb    = (ushort_t*)alloc((size_t)Nn * 512 * 2);   // interleaved K|V
  ushort_t* xb16   = (ushort_t*)alloc((size_t)Nn * 256 * 2);
  ushort_t* Wcat_t = (ushort_t*)alloc((size_t)4 * 1152 * 256 * 2);
  float*    bias_cat = (float*)alloc((size_t)4 * 1152 * 4);
  float*    bnstat = (float*)alloc(512 * 4);
  float*    pool   = (float*)alloc((size_t)Gg * 256 * 4);
  int* deg     = (int*)alloc((size_t)Nn * 4);
  int* fill    = (int*)alloc((size_t)Nn * 4);
  int* row_ptr = (int*)alloc((size_t)(Nn + 1) * 4);
  int* csr     = (int*)alloc((size_t)Ee * 4);
  (void)ws_size; (void)n_in;

  const int* srcA = edge_index;
  const int* dstA = edge_index + Ee;

  // CSR build by dst
  hipMemsetAsync(deg, 0, (size_t)Nn * 4, stream);
  hipMemsetAsync(fill, 0, (size_t)Nn * 4, stream);
  k_count<<<(Ee + 255) / 256, 256, 0, stream>>>(dstA, deg, Ee);
  k_scan<<<1, 1024, 0, stream>>>(deg, row_ptr, Nn);
  k_scatter<<<(Ee + 255) / 256, 256, 0, stream>>>(dstA, row_ptr, fill, csr, Ee);

  // weight/bias conversion (bf16, transposed concat) + composite dq rows
  k_wconv<<<dim3(8, 8, 16), dim3(32, 8), 0, stream>>>(Wq, Wk, Wv, Wskip, Wcat_t);
  k_bconv<<<16, 256, 0, stream>>>(bq, bk, bv, bskip, bias_cat);
  k_mkdq<<<dim3(68, 4), 256, 0, stream>>>(Wq, bq, We, be, Wcat_t, bias_cat);

  // input projection (fp32) + bf16 mirror
  dim3 gemm_grid(256 / BN, (Nn + BM - 1) / BM);
  k_gemm<<<gemm_grid, 256, 0, stream>>>(node_features, proj_W, proj_b, xb, xb16, Nn, 64, 256);

  int nodeBlocks = (Nn + 7) / 8;
  dim3 qkvs_grid(9, (Nn + 127) / 128);
  for (int l = 0; l < 4; ++l) {
    k_qkvs<<<qkvs_grid, 256, 0, stream>>>(xb16, Wcat_t + (size_t)l * (1152 * 256),
                                          bias_cat + l * 1152, Qb16, KVb, Sb16, Dqb, Nn);

    k_attn<<<nodeBlocks, 256, 0, stream>>>(Qb16, KVb, Dqb, edge_attr, srcA,
                                           We + (size_t)l * 4096, be + l * 256,
                                           Wbeta + (size_t)l * 768,
                                           row_ptr, csr, Sb16, xb, Nn);

    hipMemsetAsync(bnstat, 0, 512 * 4, stream);
    k_bnstats<<<512, 256, 0, stream>>>(xb, bnstat, bnstat + 256, Nn);
    k_bnapply<<<512, 256, 0, stream>>>(xb, xb16, bnstat, bnstat + 256,
                                       bn_gamma + l * 256, bn_beta + l * 256, Nn);
  }

  hipMemsetAsync(pool, 0, (size_t)Gg * 256 * 4, stream);
  k_pool<<<256, 256, 0, stream>>>(xb, batch, pool, Nn);
  k_head<<<Gg, 64, 0, stream>>>(pool, batch, head_W, head_b, out_dev, Nn);
}

// Round 7
// 1743.894 us; speedup vs baseline: 7.4616x; 7.4616x over previous
//
#include <hip/hip_runtime.h>
#include <math.h>

// ---------------------------------------------------------------------------
// AnticipatoryRestaurantGNN round 7:
//  - R6's two-node-per-wave k_attn REDONE with fully static double-buffering
//    (R6 regression root cause: kv[2][4] indexed by runtime pp -> scratch
//    spill of every KV buffer; VALUBusy 25%, HBM 1.5%).  All buffer indices
//    are now compile-time constants (bA/bB for node A ping/pong, bC/bD for
//    node B), R5-style two-phase unrolled loop.
//  - keeps R6: bf16 Q/S, edge-attr 4B gather + bpermute, head inline counts
// ---------------------------------------------------------------------------

#define EPS 1e-5f
typedef unsigned short ushort_t;
typedef unsigned int uint_t;

using f32x4 = __attribute__((ext_vector_type(4))) float;
using s16x8 = __attribute__((ext_vector_type(8))) short;
using u16x8 = __attribute__((ext_vector_type(8))) unsigned short;

__device__ __forceinline__ ushort_t f2bf(float f) {
  union { float f; uint_t u; } v; v.f = f;
  uint_t u = v.u;
  uint_t r = (u + 0x7FFFu + ((u >> 16) & 1u)) >> 16;   // RNE
  return (ushort_t)r;
}
__device__ __forceinline__ float bf2f(ushort_t h) {
  union { uint_t u; float f; } v; v.u = ((uint_t)h) << 16;
  return v.f;
}

__device__ __forceinline__ void gl_lds16(const void* g, void* l) {
  __builtin_amdgcn_global_load_lds(
      (const __attribute__((address_space(1))) void*)g,
      (__attribute__((address_space(3))) void*)l, 16, 0, 0);
}

__device__ __forceinline__ float red16(float x) {
  x += __shfl_xor(x, 1, 64);
  x += __shfl_xor(x, 2, 64);
  x += __shfl_xor(x, 4, 64);
  x += __shfl_xor(x, 8, 64);
  return x;
}

// ---------------- CSR build (by dst; dst reused across all 4 layers) -------
__global__ void k_count(const int* __restrict__ dst, int* __restrict__ deg, int n) {
  int i = blockIdx.x * 256 + threadIdx.x;
  if (i < n) atomicAdd(&deg[dst[i]], 1);
}

__global__ void k_scan(const int* __restrict__ deg, int* __restrict__ row_ptr, int n) {
  __shared__ int wsum[16];
  __shared__ int carry_s;
  int t = threadIdx.x, lane = t & 63, w = t >> 6;
  if (t == 0) { carry_s = 0; row_ptr[0] = 0; }
  __syncthreads();
  for (int base = 0; base < n; base += 1024) {
    int v = (base + t < n) ? deg[base + t] : 0;
    int x = v;
#pragma unroll
    for (int off = 1; off < 64; off <<= 1) {
      int y = __shfl_up(x, off, 64);
      if (lane >= off) x += y;
    }
    if (lane == 63) wsum[w] = x;
    __syncthreads();
    if (w == 0 && lane < 16) {
      int s = wsum[lane];
#pragma unroll
      for (int off = 1; off < 16; off <<= 1) {
        int y = __shfl_up(s, off, 64);
        if (lane >= off) s += y;
      }
      wsum[lane] = s;
    }
    __syncthreads();
    int add = (w > 0) ? wsum[w - 1] : 0;
    int incl = x + add + carry_s;
    if (base + t < n) row_ptr[base + t + 1] = incl;
    __syncthreads();
    if (t == 1023) carry_s = incl;
    __syncthreads();
  }
}

__global__ void k_scatter(const int* __restrict__ dst, const int* __restrict__ row_ptr,
                          int* __restrict__ fill, int* __restrict__ csr, int n) {
  int i = blockIdx.x * 256 + threadIdx.x;
  if (i < n) {
    int d = dst[i];
    int pos = atomicAdd(&fill[d], 1);
    csr[row_ptr[d] + pos] = i;
  }
}

// ---------------- weight convert: Wcat_t[l][n=1152][k=256] bf16 ------------
__global__ void k_wconv(const float* __restrict__ Wq, const float* __restrict__ Wk,
                        const float* __restrict__ Wv, const float* __restrict__ Ws,
                        ushort_t* __restrict__ Wcat_t) {
  __shared__ float tile[32][33];
  int l = blockIdx.z >> 2, sel = blockIdx.z & 3;
  const float* W = (sel == 0) ? Wq : (sel == 1) ? Wk : (sel == 2) ? Wv : Ws;
  W += (size_t)l * 65536;
  int k0 = blockIdx.x * 32, n0 = blockIdx.y * 32;
  int tx = threadIdx.x, ty = threadIdx.y;           // 32 x 8
#pragma unroll
  for (int i = 0; i < 32; i += 8) tile[ty + i][tx] = W[(size_t)(k0 + ty + i) * 256 + n0 + tx];
  __syncthreads();
  ushort_t* dst = Wcat_t + (size_t)l * (1152 * 256) + (size_t)(sel * 256 + n0) * 256 + k0;
#pragma unroll
  for (int i = 0; i < 32; i += 8) dst[(size_t)(ty + i) * 256 + tx] = f2bf(tile[tx][ty + i]);
}

// composite rows 1024..1091: M[ci][j] = sum_{c in head(j)} Wq[ci][c]*w2[c]
__global__ void k_mkdq(const float* __restrict__ Wq, const float* __restrict__ bq,
                       const float* __restrict__ We, const float* __restrict__ be,
                       ushort_t* __restrict__ Wcat_t, float* __restrict__ bias_cat) {
  int j = blockIdx.x;        // 0..67
  int l = blockIdx.y;        // 0..3
  int ci = threadIdx.x;      // 0..255
  __shared__ float w2[64];
  int h = (j < 64) ? (j >> 4) : (j - 64);
  if (ci < 64) {
    float v;
    if (j < 64) v = We[(size_t)l * 4096 + (j & 15) * 256 + h * 64 + ci];
    else        v = be[l * 256 + h * 64 + ci];
    w2[ci] = v * 0.125f;
  }
  __syncthreads();
  const float* Wq_l = Wq + (size_t)l * 65536;
  float acc = 0.f;
#pragma unroll 8
  for (int c = 0; c < 64; ++c) acc += Wq_l[(size_t)ci * 256 + h * 64 + c] * w2[c];
  Wcat_t[(size_t)l * (1152 * 256) + (size_t)(1024 + j) * 256 + ci] = f2bf(acc);
  if (ci == 0) {
    const float* bq_l = bq + l * 256;
    float d0 = 0.f;
    for (int c = 0; c < 64; ++c) d0 += bq_l[h * 64 + c] * w2[c];
    bias_cat[l * 1152 + 1024 + j] = d0;
  }
}

__global__ void k_bconv(const float* __restrict__ bq, const float* __restrict__ bk,
                        const float* __restrict__ bv, const float* __restrict__ bs,
                        float* __restrict__ bias_cat) {
  int idx = blockIdx.x * 256 + threadIdx.x;   // 4096 total
  if (idx >= 4096) return;
  int l = idx >> 10, rest = idx & 1023, sel = rest >> 8, c = rest & 255;
  const float* p = (sel == 0) ? bq : (sel == 1) ? bk : (sel == 2) ? bv : bs;
  bias_cat[l * 1152 + rest] = p[l * 256 + c];
}

// ---------------- fp32 tiled GEMM (input projection only) ------------------
#define BM 128
#define BN 64
#define BK 16
__global__ __launch_bounds__(256) void k_gemm(
    const float* __restrict__ A, const float* __restrict__ B,
    const float* __restrict__ bias, float* __restrict__ C,
    ushort_t* __restrict__ C16, int M, int Kd, int Nd) {
  __shared__ float As[BK][BM + 4];
  __shared__ float Bs[BK][BN + 4];
  int t = threadIdx.x;
  int tx = t & 15, ty = t >> 4;
  int row0 = blockIdx.y * BM, col0 = blockIdx.x * BN;
  float acc[8][4] = {};
  for (int k0 = 0; k0 < Kd; k0 += BK) {
#pragma unroll
    for (int i = 0; i < 2; ++i) {
      int idx = t + i * 256;
      int r = idx >> 2, kk = (idx & 3) * 4;
      float4 a = make_float4(0.f, 0.f, 0.f, 0.f);
      if (row0 + r < M) a = *(const float4*)(A + (size_t)(row0 + r) * Kd + k0 + kk);
      As[kk + 0][r] = a.x; As[kk + 1][r] = a.y; As[kk + 2][r] = a.z; As[kk + 3][r] = a.w;
    }
    {
      int kk = t >> 4, cc = (t & 15) * 4;
      float4 b = *(const float4*)(B + (size_t)(k0 + kk) * Nd + col0 + cc);
      Bs[kk][cc] = b.x; Bs[kk][cc + 1] = b.y; Bs[kk][cc + 2] = b.z; Bs[kk][cc + 3] = b.w;
    }
    __syncthreads();
#pragma unroll
    for (int kk = 0; kk < BK; ++kk) {
      float ar[8], br[4];
#pragma unroll
      for (int i = 0; i < 8; ++i) ar[i] = As[kk][ty * 8 + i];
#pragma unroll
      for (int j = 0; j < 4; ++j) br[j] = Bs[kk][tx * 4 + j];
#pragma unroll
      for (int i = 0; i < 8; ++i)
#pragma unroll
        for (int j = 0; j < 4; ++j) acc[i][j] += ar[i] * br[j];
    }
    __syncthreads();
  }
#pragma unroll
  for (int i = 0; i < 8; ++i) {
    int r = row0 + ty * 8 + i;
    if (r < M) {
      int c = col0 + tx * 4;
      float4 o;
      o.x = acc[i][0] + bias[c + 0];
      o.y = acc[i][1] + bias[c + 1];
      o.z = acc[i][2] + bias[c + 2];
      o.w = acc[i][3] + bias[c + 3];
      *(float4*)(C + (size_t)r * Nd + c) = o;
      ushort4 h;
      h.x = f2bf(o.x); h.y = f2bf(o.y); h.z = f2bf(o.z); h.w = f2bf(o.w);
      *(ushort4*)(C16 + (size_t)r * Nd + c) = h;
    }
  }
}

// ---------------- fused QKVS+Dq bf16 MFMA GEMM -----------------------------
// C[M x 1152] = A[M x 256] @ Bt^T  (Bt is [1152][256], k-contiguous)
__global__ __launch_bounds__(256) void k_qkvs(
    const ushort_t* __restrict__ A, const ushort_t* __restrict__ Bt,
    const float* __restrict__ bias, ushort_t* __restrict__ Qb16,
    ushort_t* __restrict__ KVb, ushort_t* __restrict__ Sb16,
    float* __restrict__ Dqb, int M) {
  __shared__ short lds_a[8192];   // 128 x 64 bf16 (swizzled granules)
  __shared__ short lds_b[8192];
  int t = threadIdx.x;
  int lane = t & 63, wv = t >> 6;
  int row0 = blockIdx.y * 128, col0 = blockIdx.x * 128;

  f32x4 acc[4][4];
#pragma unroll
  for (int im = 0; im < 4; ++im)
#pragma unroll
    for (int in = 0; in < 4; ++in) acc[im][in] = (f32x4){0.f, 0.f, 0.f, 0.f};

  int ln16 = lane & 15, q = lane >> 4;
  int mbase = (wv >> 1) * 64;
  int nbase = (wv & 1) * 64;

  for (int kk = 0; kk < 4; ++kk) {
    int k0 = kk * 64;
    __syncthreads();          // protect previous iteration's LDS reads
#pragma unroll
    for (int i = 0; i < 4; ++i) {
      int gi = i * 256 + t;
      int r = gi >> 3, c = (gi & 7) ^ (r & 7);
      int gr = row0 + r; if (gr > M - 1) gr = M - 1;
      gl_lds16(A + (size_t)gr * 256 + k0 + c * 8, &((int4*)lds_a)[gi]);
      gl_lds16(Bt + (size_t)(col0 + r) * 256 + k0 + c * 8, &((int4*)lds_b)[gi]);
    }
    __syncthreads();          // drains vmcnt(0) then barrier
#pragma unroll
    for (int kc = 0; kc < 2; ++kc) {
      s16x8 af[4], bf[4];
      int cq = kc * 4 + q;
#pragma unroll
      for (int im = 0; im < 4; ++im) {
        int r = mbase + im * 16 + ln16;
        af[im] = ((const s16x8*)lds_a)[r * 8 + (cq ^ (r & 7))];
      }
#pragma unroll
      for (int in = 0; in < 4; ++in) {
        int r = nbase + in * 16 + ln16;
        bf[in] = ((const s16x8*)lds_b)[r * 8 + (cq ^ (r & 7))];
      }
#pragma unroll
      for (int im = 0; im < 4; ++im)
#pragma unroll
        for (int in = 0; in < 4; ++in)
          acc[im][in] = __builtin_amdgcn_mfma_f32_16x16x32_bf16(af[im], bf[in], acc[im][in], 0, 0, 0);
    }
  }

  // epilogue: C[m = q*4+j][n = ln16] per tile.
#pragma unroll
  for (int in = 0; in < 4; ++in) {
    int ncol = col0 + nbase + in * 16 + ln16;
    int lc = ncol & 255;
    float bz = bias[ncol];
#pragma unroll
    for (int im = 0; im < 4; ++im) {
#pragma unroll
      for (int j = 0; j < 4; ++j) {
        int mr = row0 + mbase + im * 16 + q * 4 + j;
        if (mr < M) {
          float v = acc[im][in][j] + bz;
          if (ncol < 256)       Qb16[(size_t)mr * 256 + lc] = f2bf(v);
          else if (ncol < 512)  KVb[(size_t)mr * 512 + (lc >> 2) * 8 + (lc & 3)] = f2bf(v);
          else if (ncol < 768)  KVb[(size_t)mr * 512 + (lc >> 2) * 8 + (lc & 3) + 4] = f2bf(v);
          else if (ncol < 1024) Sb16[(size_t)mr * 256 + lc] = f2bf(v);
          else { int j2 = ncol - 1024; if (j2 < 68) Dqb[(size_t)mr * 68 + j2] = v; }
        }
      }
    }
  }
}

// ---------------- attention + beta-gate blend: TWO nodes per wave ----------
// Static double-buffering: bA/bB = node-A ping/pong, bC/bD = node-B ping/pong.
// Every buffer index is a compile-time constant (no scratch spill).
__global__ __launch_bounds__(256) void k_attn(
    const ushort_t* __restrict__ Qp, const ushort_t* __restrict__ KVm,
    const float* __restrict__ Dqp,
    const float* __restrict__ ea_g, const int* __restrict__ srcA,
    const float* __restrict__ We_l, const float* __restrict__ be_l,
    const float* __restrict__ Wb, const int* __restrict__ row_ptr,
    const int* __restrict__ csr, const ushort_t* __restrict__ Sp,
    float* __restrict__ xout, int nNodes) {
  __shared__ float sWb[768];
  int t = threadIdx.x;
  sWb[t] = Wb[t];
  sWb[t + 256] = Wb[t + 256];
  sWb[t + 512] = Wb[t + 512];
  __syncthreads();
  int lane = t & 63;
  int t16 = lane & 15;
  int nA = blockIdx.x * 8 + (t >> 6) * 2;
  if (nA >= nNodes) return;
  int nB = nA + 1;
  bool hasB = nB < nNodes;

  float4 be4 = *(const float4*)(be_l + 4 * lane);

  ushort4 qhA = *(const ushort4*)(Qp + (size_t)nA * 256 + 4 * lane);
  float4 qsA = make_float4(bf2f(qhA.x) * 0.125f, bf2f(qhA.y) * 0.125f,
                           bf2f(qhA.z) * 0.125f, bf2f(qhA.w) * 0.125f);
  float dqA = Dqp[(size_t)nA * 68 + lane];
  float qbeA = Dqp[(size_t)nA * 68 + 64 + (lane >> 4)];
  int begA = row_ptr[nA], endA = row_ptr[nA + 1];

  float4 qsB = make_float4(0.f, 0.f, 0.f, 0.f);
  float dqB = 0.f, qbeB = 0.f;
  int begB = 0, endB = 0;
  if (hasB) {
    ushort4 qhB = *(const ushort4*)(Qp + (size_t)nB * 256 + 4 * lane);
    qsB = make_float4(bf2f(qhB.x) * 0.125f, bf2f(qhB.y) * 0.125f,
                      bf2f(qhB.z) * 0.125f, bf2f(qhB.w) * 0.125f);
    dqB = Dqp[(size_t)nB * 68 + lane];
    qbeB = Dqp[(size_t)nB * 68 + 64 + (lane >> 4)];
    begB = row_ptr[nB]; endB = row_ptr[nB + 1];
  }

  float mA = -INFINITY, dnA = 0.f, waA = 0.f;
  float mB = -INFINITY, dnB = 0.f, waB = 0.f;
  float4 acA = make_float4(0.f, 0.f, 0.f, 0.f);
  float4 acB = make_float4(0.f, 0.f, 0.f, 0.f);

  int baseA = begA, baseB = begB;
  while (baseA < endA || baseB < endB) {
    int cntA = (baseA < endA) ? min(64, endA - baseA) : 0;
    int cntB = (baseB < endB) ? min(64, endB - baseB) : 0;
    int eA = 0, sA = 0, eB = 0, sB = 0;
    if (lane < cntA) { eA = csr[baseA + lane]; sA = srcA[eA]; }
    if (lane < cntB) { eB = csr[baseB + lane]; sB = srcA[eB]; }

    // static buffers; only constant indices after unrolling
    u16x8 bA[4], bB[4], bC[4], bD[4];
    float eaA0 = 0.f, eaA1 = 0.f, eaB0 = 0.f, eaB1 = 0.f;

    auto ld4 = [&](u16x8* buf, float& eaR, int eL_, int sL_, int cnt, int g4) {
      if (g4 >= cnt) return;
      int esel = g4 + (lane >> 4);              // <= 63 whenever g4 < cnt
      int eid = __shfl(eL_, esel, 64);
      eaR = ea_g[(size_t)eid * 16 + t16];
#pragma unroll
      for (int jj = 0; jj < 4; ++jj) {
        if (g4 + jj < cnt) {
          int s = __shfl(sL_, g4 + jj, 64);
          buf[jj] = *(const u16x8*)(KVm + (size_t)s * 512 + lane * 8);
        }
      }
    };
    auto proc4 = [&](const u16x8* buf, float eaR, int g4, int cnt,
                     float& m, float& dn, float& wa, float4& ac,
                     const float4& qs, float dqv, float qbe) {
#pragma unroll
      for (int jj = 0; jj < 4; ++jj) {
        if (g4 + jj < cnt) {
          float eat = __shfl(eaR, (jj << 4) | t16, 64);
          float part = qs.x * bf2f(buf[jj][0]) + qs.y * bf2f(buf[jj][1]) +
                       qs.z * bf2f(buf[jj][2]) + qs.w * bf2f(buf[jj][3]) + eat * dqv;
          float p = red16(part) + qbe;
          float mn = fmaxf(m, p);
          float scl = __expf(m - mn);   // -inf first time -> 0
          float w = __expf(p - mn);
          m = mn;
          dn = dn * scl + w;
          ac.x = ac.x * scl + w * bf2f(buf[jj][4]);
          ac.y = ac.y * scl + w * bf2f(buf[jj][5]);
          ac.z = ac.z * scl + w * bf2f(buf[jj][6]);
          ac.w = ac.w * scl + w * bf2f(buf[jj][7]);
          wa = wa * scl + w * eat;
        }
      }
    };

    ld4(bA, eaA0, eA, sA, cntA, 0);
    ld4(bC, eaB0, eB, sB, cntB, 0);
    int gmax = max(cntA, cntB);
    for (int g4 = 0; g4 < gmax; g4 += 8) {
      ld4(bB, eaA1, eA, sA, cntA, g4 + 4);
      ld4(bD, eaB1, eB, sB, cntB, g4 + 4);
      proc4(bA, eaA0, g4, cntA, mA, dnA, waA, acA, qsA, dqA, qbeA);
      proc4(bC, eaB0, g4, cntB, mB, dnB, waB, acB, qsB, dqB, qbeB);
      if (g4 + 4 >= gmax) break;
      ld4(bA, eaA0, eA, sA, cntA, g4 + 8);
      ld4(bC, eaB0, eB, sB, cntB, g4 + 8);
      proc4(bB, eaA1, g4 + 4, cntA, mA, dnA, waA, acA, qsA, dqA, qbeA);
      proc4(bD, eaB1, g4 + 4, cntB, mB, dnB, waB, acB, qsB, dqB, qbeB);
    }
    baseA += 64;
    baseB += 64;
  }

  // epilogue (shared We loads for the node pair)
  float4 oA = make_float4(0.f, 0.f, 0.f, 0.f);
  float4 oB = make_float4(0.f, 0.f, 0.f, 0.f);
  float waccA = 0.f, waccB = 0.f;
  if (endA > begA) {
    float inv = 1.0f / dnA;
    oA.x = acA.x * inv + be4.x; oA.y = acA.y * inv + be4.y;
    oA.z = acA.z * inv + be4.z; oA.w = acA.w * inv + be4.w;
    waccA = waA * inv;
  }
  if (hasB && endB > begB) {
    float inv = 1.0f / dnB;
    oB.x = acB.x * inv + be4.x; oB.y = acB.y * inv + be4.y;
    oB.z = acB.z * inv + be4.z; oB.w = acB.w * inv + be4.w;
    waccB = waB * inv;
  }
  int lanebase = lane & 48;
#pragma unroll
  for (int tt = 0; tt < 16; ++tt) {
    float4 w4 = *(const float4*)(We_l + tt * 256 + 4 * lane);
    float wvA = __shfl(waccA, lanebase + tt, 64);
    float wvB = __shfl(waccB, lanebase + tt, 64);
    oA.x += wvA * w4.x; oA.y += wvA * w4.y; oA.z += wvA * w4.z; oA.w += wvA * w4.w;
    oB.x += wvB * w4.x; oB.y += wvB * w4.y; oB.z += wvB * w4.z; oB.w += wvB * w4.w;
  }

  // fused beta-gate blend (node A, then node B)
  int c = 4 * lane;
#pragma unroll
  for (int which = 0; which < 2; ++which) {
    if (which == 1 && !hasB) break;
    int n = (which == 0) ? nA : nB;
    float4 o = (which == 0) ? oA : oB;
    ushort4 rh = *(const ushort4*)(Sp + (size_t)n * 256 + 4 * lane);
    float4 r = make_float4(bf2f(rh.x), bf2f(rh.y), bf2f(rh.z), bf2f(rh.w));
    float z = o.x * sWb[c] + o.y * sWb[c + 1] + o.z * sWb[c + 2] + o.w * sWb[c + 3]
            + r.x * sWb[256 + c] + r.y * sWb[257 + c] + r.z * sWb[258 + c] + r.w * sWb[259 + c]
            + (o.x - r.x) * sWb[512 + c] + (o.y - r.y) * sWb[513 + c]
            + (o.z - r.z) * sWb[514 + c] + (o.w - r.w) * sWb[515 + c];
#pragma unroll
    for (int off = 1; off < 64; off <<= 1) z += __shfl_xor(z, off, 64);
    float beta = 1.0f / (1.0f + __expf(-z));
    float4 xn;
    xn.x = beta * r.x + (1.f - beta) * o.x;
    xn.y = beta * r.y + (1.f - beta) * o.y;
    xn.z = beta * r.z + (1.f - beta) * o.z;
    xn.w = beta * r.w + (1.f - beta) * o.w;
    *(float4*)(xout + (size_t)n * 256 + 4 * lane) = xn;
  }
}

// ---------------- batchnorm ------------------------------------------------
__global__ void k_bnstats(const float* __restrict__ x, float* __restrict__ sums,
                          float* __restrict__ sums2, int nRows) {
  int c = threadIdx.x;
  int rpb = (nRows + gridDim.x - 1) / gridDim.x;
  int r0 = blockIdx.x * rpb;
  int r1 = min(nRows, r0 + rpb);
  float s = 0.f, s2 = 0.f;
  for (int r = r0; r < r1; ++r) {
    float v = x[(size_t)r * 256 + c];
    s += v;
    s2 += v * v;
  }
  atomicAdd(&sums[c], s);
  atomicAdd(&sums2[c], s2);
}

__global__ __launch_bounds__(256) void k_bnapply(
    float* __restrict__ x, ushort_t* __restrict__ x16,
    const float* __restrict__ sums, const float* __restrict__ sums2,
    const float* __restrict__ gamma, const float* __restrict__ betap, int nRows) {
  int total4 = nRows * 64;
  float invN = 1.0f / (float)nRows;
  for (int i4 = blockIdx.x * 256 + threadIdx.x; i4 < total4; i4 += gridDim.x * 256) {
    int c4 = (i4 & 63) * 4;
    float4 xv = *(const float4*)(x + (size_t)i4 * 4);
    float4 s = *(const float4*)(sums + c4);
    float4 s2 = *(const float4*)(sums2 + c4);
    float4 g = *(const float4*)(gamma + c4);
    float4 b = *(const float4*)(betap + c4);
    float mu0 = s.x * invN, mu1 = s.y * invN, mu2 = s.z * invN, mu3 = s.w * invN;
    float sc0 = rsqrtf(s2.x * invN - mu0 * mu0 + EPS) * g.x;
    float sc1 = rsqrtf(s2.y * invN - mu1 * mu1 + EPS) * g.y;
    float sc2 = rsqrtf(s2.z * invN - mu2 * mu2 + EPS) * g.z;
    float sc3 = rsqrtf(s2.w * invN - mu3 * mu3 + EPS) * g.w;
    float4 v;
    v.x = (xv.x - mu0) * sc0 + b.x;
    v.y = (xv.y - mu1) * sc1 + b.y;
    v.z = (xv.z - mu2) * sc2 + b.z;
    v.w = (xv.w - mu3) * sc3 + b.w;
    v.x = v.x >= 0.f ? v.x : 0.1f * v.x;
    v.y = v.y >= 0.f ? v.y : 0.1f * v.y;
    v.z = v.z >= 0.f ? v.z : 0.1f * v.z;
    v.w = v.w >= 0.f ? v.w : 0.1f * v.w;
    *(float4*)(x + (size_t)i4 * 4) = v;
    ushort4 h;
    h.x = f2bf(v.x); h.y = f2bf(v.y); h.z = f2bf(v.z); h.w = f2bf(v.w);
    *(ushort4*)(x16 + (size_t)i4 * 4) = h;
  }
}

// ---------------- pooling + head -------------------------------------------
__global__ void k_pool(const float* __restrict__ x, const int* __restrict__ batch,
                       float* __restrict__ pool, int nRows) {
  int c = threadIdx.x;
  int rpb = (nRows + gridDim.x - 1) / gridDim.x;
  int r0 = blockIdx.x * rpb;
  int r1 = min(nRows, r0 + rpb);
  float acc = 0.f;
  int gc = -1;
  for (int r = r0; r < r1; ++r) {
    int g = batch[r];
    if (g != gc) {
      if (gc >= 0) atomicAdd(&pool[gc * 256 + c], acc);
      acc = 0.f;
      gc = g;
    }
    acc += x[(size_t)r * 256 + c];
  }
  if (gc >= 0) atomicAdd(&pool[gc * 256 + c], acc);
}

// head with inline per-graph counts (batch sorted -> binary search)
__global__ void k_head(const float* __restrict__ pool, const int* __restrict__ batch,
                       const float* __restrict__ hW, const float* __restrict__ hb,
                       float* __restrict__ outp, int nRows) {
  int g = blockIdx.x, lane = threadIdx.x;
  int lo = 0, hi = nRows;
  while (lo < hi) { int mid = (lo + hi) >> 1; if (batch[mid] < g) lo = mid + 1; else hi = mid; }
  int lb = lo;
  lo = 0; hi = nRows;
  while (lo < hi) { int mid = (lo + hi) >> 1; if (batch[mid] < g + 1) lo = mid + 1; else hi = mid; }
  float cnt = fmaxf((float)(lo - lb), 1.0f);
  float z = 0.f;
#pragma unroll
  for (int i = 0; i < 4; ++i) {
    int c = lane + i * 64;
    float s = pool[g * 256 + c];
    z += (s / cnt) * hW[c] + s * hW[256 + c];
  }
#pragma unroll
  for (int off = 1; off < 64; off <<= 1) z += __shfl_xor(z, off, 64);
  if (lane == 0) outp[g] = z + hb[0];
}

// ---------------------------------------------------------------------------
extern "C" void kernel_launch(void* const* d_in, const int* in_sizes, int n_in,
                              void* d_out, int out_size, void* d_ws, size_t ws_size,
                              hipStream_t stream) {
  const float* node_features = (const float*)d_in[0];
  const int*   edge_index    = (const int*)d_in[1];
  const float* edge_attr     = (const float*)d_in[2];
  const int*   batch         = (const int*)d_in[3];
  const float* proj_W  = (const float*)d_in[4];
  const float* proj_b  = (const float*)d_in[5];
  const float* Wq      = (const float*)d_in[6];
  const float* bq      = (const float*)d_in[7];
  const float* Wk      = (const float*)d_in[8];
  const float* bk      = (const float*)d_in[9];
  const float* Wv      = (const float*)d_in[10];
  const float* bv      = (const float*)d_in[11];
  const float* We      = (const float*)d_in[12];
  const float* be      = (const float*)d_in[13];
  const float* Wskip   = (const float*)d_in[14];
  const float* bskip   = (const float*)d_in[15];
  const float* Wbeta   = (const float*)d_in[16];
  const float* bn_gamma= (const float*)d_in[17];
  const float* bn_beta = (const float*)d_in[18];
  const float* head_W  = (const float*)d_in[19];
  const float* head_b  = (const float*)d_in[20];
  float* out_dev = (float*)d_out;

  const int Nn = in_sizes[0] / 64;   // 50000
  const int Ee = in_sizes[1] / 2;    // 500000
  const int Gg = out_size;           // 64

  char* ws = (char*)d_ws;
  size_t off = 0;
  auto alloc = [&](size_t bytes) -> void* {
    void* p = ws + off;
    off += (bytes + 255) & ~(size_t)255;
    return p;
  };
  float*    xb     = (float*)alloc((size_t)Nn * 256 * 4);
  float*    Dqb    = (float*)alloc((size_t)Nn * 68 * 4);
  ushort_t* Qb16   = (ushort_t*)alloc((size_t)Nn * 256 * 2);
  ushort_t* Sb16   = (ushort_t*)alloc((size_t)Nn * 256 * 2);
  ushort_t* KVb    = (ushort_t*)alloc((size_t)Nn * 512 * 2);   // interleaved K|V
  ushort_t* xb16   = (ushort_t*)alloc((size_t)Nn * 256 * 2);
  ushort_t* Wcat_t = (ushort_t*)alloc((size_t)4 * 1152 * 256 * 2);
  float*    bias_cat = (float*)alloc((size_t)4 * 1152 * 4);
  float*    bnstat = (float*)alloc(512 * 4);
  float*    pool   = (float*)alloc((size_t)Gg * 256 * 4);
  int* deg     = (int*)alloc((size_t)Nn * 4);
  int* fill    = (int*)alloc((size_t)Nn * 4);
  int* row_ptr = (int*)alloc((size_t)(Nn + 1) * 4);
  int* csr     = (int*)alloc((size_t)Ee * 4);
  (void)ws_size; (void)n_in;

  const int* srcA = edge_index;
  const int* dstA = edge_index + Ee;

  // CSR build by dst
  hipMemsetAsync(deg, 0, (size_t)Nn * 4, stream);
  hipMemsetAsync(fill, 0, (size_t)Nn * 4, stream);
  k_count<<<(Ee + 255) / 256, 256, 0, stream>>>(dstA, deg, Ee);
  k_scan<<<1, 1024, 0, stream>>>(deg, row_ptr, Nn);
  k_scatter<<<(Ee + 255) / 256, 256, 0, stream>>>(dstA, row_ptr, fill, csr, Ee);

  // weight/bias conversion (bf16, transposed concat) + composite dq rows
  k_wconv<<<dim3(8, 8, 16), dim3(32, 8), 0, stream>>>(Wq, Wk, Wv, Wskip, Wcat_t);
  k_bconv<<<16, 256, 0, stream>>>(bq, bk, bv, bskip, bias_cat);
  k_mkdq<<<dim3(68, 4), 256, 0, stream>>>(Wq, bq, We, be, Wcat_t, bias_cat);

  // input projection (fp32) + bf16 mirror
  dim3 gemm_grid(256 / BN, (Nn + BM - 1) / BM);
  k_gemm<<<gemm_grid, 256, 0, stream>>>(node_features, proj_W, proj_b, xb, xb16, Nn, 64, 256);

  int nodeBlocks = (Nn + 7) / 8;
  dim3 qkvs_grid(9, (Nn + 127) / 128);
  for (int l = 0; l < 4; ++l) {
    k_qkvs<<<qkvs_grid, 256, 0, stream>>>(xb16, Wcat_t + (size_t)l * (1152 * 256),
                                          bias_cat + l * 1152, Qb16, KVb, Sb16, Dqb, Nn);

    k_attn<<<nodeBlocks, 256, 0, stream>>>(Qb16, KVb, Dqb, edge_attr, srcA,
                                           We + (size_t)l * 4096, be + l * 256,
                                           Wbeta + (size_t)l * 768,
                                           row_ptr, csr, Sb16, xb, Nn);

    hipMemsetAsync(bnstat, 0, 512 * 4, stream);
    k_bnstats<<<512, 256, 0, stream>>>(xb, bnstat, bnstat + 256, Nn);
    k_bnapply<<<512, 256, 0, stream>>>(xb, xb16, bnstat, bnstat + 256,
                                       bn_gamma + l * 256, bn_beta + l * 256, Nn);
  }

  hipMemsetAsync(pool, 0, (size_t)Gg * 256 * 4, stream);
  k_pool<<<256, 256, 0, stream>>>(xb, batch, pool, Nn);
  k_head<<<Gg, 64, 0, stream>>>(pool, batch, head_W, head_b, out_dev, Nn);
}

// Round 8
// 1392.891 us; speedup vs baseline: 9.3419x; 1.2520x over previous
//
#include <hip/hip_runtime.h>
#include <math.h>

// ---------------------------------------------------------------------------
// AnticipatoryRestaurantGNN round 8:
//  - k_attn back to ONE node per wave (R7 two-node variant: VGPR 96 ->
//    occupancy 19% -> 211us; R5 one-node: VGPR 64, occ 38%, 138us).
//  - NEW: block-softmax — one rescale of (dn,ac,wa) per 4-edge group
//    (exact), 4 independent score computations for ILP.  Serial chain
//    ~10 ops/edge -> ~5 ops/group.
//  - keeps: bf16 Q/S, 4B edge-attr gather + shfl distribute, dq via GEMM,
//    static ping-pong KV buffers (compile-time indices only).
// ---------------------------------------------------------------------------

#define EPS 1e-5f
typedef unsigned short ushort_t;
typedef unsigned int uint_t;

using f32x4 = __attribute__((ext_vector_type(4))) float;
using s16x8 = __attribute__((ext_vector_type(8))) short;
using u16x8 = __attribute__((ext_vector_type(8))) unsigned short;

__device__ __forceinline__ ushort_t f2bf(float f) {
  union { float f; uint_t u; } v; v.f = f;
  uint_t u = v.u;
  uint_t r = (u + 0x7FFFu + ((u >> 16) & 1u)) >> 16;   // RNE
  return (ushort_t)r;
}
__device__ __forceinline__ float bf2f(ushort_t h) {
  union { uint_t u; float f; } v; v.u = ((uint_t)h) << 16;
  return v.f;
}

__device__ __forceinline__ void gl_lds16(const void* g, void* l) {
  __builtin_amdgcn_global_load_lds(
      (const __attribute__((address_space(1))) void*)g,
      (__attribute__((address_space(3))) void*)l, 16, 0, 0);
}

__device__ __forceinline__ float red16(float x) {
  x += __shfl_xor(x, 1, 64);
  x += __shfl_xor(x, 2, 64);
  x += __shfl_xor(x, 4, 64);
  x += __shfl_xor(x, 8, 64);
  return x;
}

// ---------------- CSR build (by dst; dst reused across all 4 layers) -------
__global__ void k_count(const int* __restrict__ dst, int* __restrict__ deg, int n) {
  int i = blockIdx.x * 256 + threadIdx.x;
  if (i < n) atomicAdd(&deg[dst[i]], 1);
}

__global__ void k_scan(const int* __restrict__ deg, int* __restrict__ row_ptr, int n) {
  __shared__ int wsum[16];
  __shared__ int carry_s;
  int t = threadIdx.x, lane = t & 63, w = t >> 6;
  if (t == 0) { carry_s = 0; row_ptr[0] = 0; }
  __syncthreads();
  for (int base = 0; base < n; base += 1024) {
    int v = (base + t < n) ? deg[base + t] : 0;
    int x = v;
#pragma unroll
    for (int off = 1; off < 64; off <<= 1) {
      int y = __shfl_up(x, off, 64);
      if (lane >= off) x += y;
    }
    if (lane == 63) wsum[w] = x;
    __syncthreads();
    if (w == 0 && lane < 16) {
      int s = wsum[lane];
#pragma unroll
      for (int off = 1; off < 16; off <<= 1) {
        int y = __shfl_up(s, off, 64);
        if (lane >= off) s += y;
      }
      wsum[lane] = s;
    }
    __syncthreads();
    int add = (w > 0) ? wsum[w - 1] : 0;
    int incl = x + add + carry_s;
    if (base + t < n) row_ptr[base + t + 1] = incl;
    __syncthreads();
    if (t == 1023) carry_s = incl;
    __syncthreads();
  }
}

__global__ void k_scatter(const int* __restrict__ dst, const int* __restrict__ row_ptr,
                          int* __restrict__ fill, int* __restrict__ csr, int n) {
  int i = blockIdx.x * 256 + threadIdx.x;
  if (i < n) {
    int d = dst[i];
    int pos = atomicAdd(&fill[d], 1);
    csr[row_ptr[d] + pos] = i;
  }
}

// ---------------- weight convert: Wcat_t[l][n=1152][k=256] bf16 ------------
__global__ void k_wconv(const float* __restrict__ Wq, const float* __restrict__ Wk,
                        const float* __restrict__ Wv, const float* __restrict__ Ws,
                        ushort_t* __restrict__ Wcat_t) {
  __shared__ float tile[32][33];
  int l = blockIdx.z >> 2, sel = blockIdx.z & 3;
  const float* W = (sel == 0) ? Wq : (sel == 1) ? Wk : (sel == 2) ? Wv : Ws;
  W += (size_t)l * 65536;
  int k0 = blockIdx.x * 32, n0 = blockIdx.y * 32;
  int tx = threadIdx.x, ty = threadIdx.y;           // 32 x 8
#pragma unroll
  for (int i = 0; i < 32; i += 8) tile[ty + i][tx] = W[(size_t)(k0 + ty + i) * 256 + n0 + tx];
  __syncthreads();
  ushort_t* dst = Wcat_t + (size_t)l * (1152 * 256) + (size_t)(sel * 256 + n0) * 256 + k0;
#pragma unroll
  for (int i = 0; i < 32; i += 8) dst[(size_t)(ty + i) * 256 + tx] = f2bf(tile[tx][ty + i]);
}

// composite rows 1024..1091: M[ci][j] = sum_{c in head(j)} Wq[ci][c]*w2[c]
__global__ void k_mkdq(const float* __restrict__ Wq, const float* __restrict__ bq,
                       const float* __restrict__ We, const float* __restrict__ be,
                       ushort_t* __restrict__ Wcat_t, float* __restrict__ bias_cat) {
  int j = blockIdx.x;        // 0..67
  int l = blockIdx.y;        // 0..3
  int ci = threadIdx.x;      // 0..255
  __shared__ float w2[64];
  int h = (j < 64) ? (j >> 4) : (j - 64);
  if (ci < 64) {
    float v;
    if (j < 64) v = We[(size_t)l * 4096 + (j & 15) * 256 + h * 64 + ci];
    else        v = be[l * 256 + h * 64 + ci];
    w2[ci] = v * 0.125f;
  }
  __syncthreads();
  const float* Wq_l = Wq + (size_t)l * 65536;
  float acc = 0.f;
#pragma unroll 8
  for (int c = 0; c < 64; ++c) acc += Wq_l[(size_t)ci * 256 + h * 64 + c] * w2[c];
  Wcat_t[(size_t)l * (1152 * 256) + (size_t)(1024 + j) * 256 + ci] = f2bf(acc);
  if (ci == 0) {
    const float* bq_l = bq + l * 256;
    float d0 = 0.f;
    for (int c = 0; c < 64; ++c) d0 += bq_l[h * 64 + c] * w2[c];
    bias_cat[l * 1152 + 1024 + j] = d0;
  }
}

__global__ void k_bconv(const float* __restrict__ bq, const float* __restrict__ bk,
                        const float* __restrict__ bv, const float* __restrict__ bs,
                        float* __restrict__ bias_cat) {
  int idx = blockIdx.x * 256 + threadIdx.x;   // 4096 total
  if (idx >= 4096) return;
  int l = idx >> 10, rest = idx & 1023, sel = rest >> 8, c = rest & 255;
  const float* p = (sel == 0) ? bq : (sel == 1) ? bk : (sel == 2) ? bv : bs;
  bias_cat[l * 1152 + rest] = p[l * 256 + c];
}

// ---------------- fp32 tiled GEMM (input projection only) ------------------
#define BM 128
#define BN 64
#define BK 16
__global__ __launch_bounds__(256) void k_gemm(
    const float* __restrict__ A, const float* __restrict__ B,
    const float* __restrict__ bias, float* __restrict__ C,
    ushort_t* __restrict__ C16, int M, int Kd, int Nd) {
  __shared__ float As[BK][BM + 4];
  __shared__ float Bs[BK][BN + 4];
  int t = threadIdx.x;
  int tx = t & 15, ty = t >> 4;
  int row0 = blockIdx.y * BM, col0 = blockIdx.x * BN;
  float acc[8][4] = {};
  for (int k0 = 0; k0 < Kd; k0 += BK) {
#pragma unroll
    for (int i = 0; i < 2; ++i) {
      int idx = t + i * 256;
      int r = idx >> 2, kk = (idx & 3) * 4;
      float4 a = make_float4(0.f, 0.f, 0.f, 0.f);
      if (row0 + r < M) a = *(const float4*)(A + (size_t)(row0 + r) * Kd + k0 + kk);
      As[kk + 0][r] = a.x; As[kk + 1][r] = a.y; As[kk + 2][r] = a.z; As[kk + 3][r] = a.w;
    }
    {
      int kk = t >> 4, cc = (t & 15) * 4;
      float4 b = *(const float4*)(B + (size_t)(k0 + kk) * Nd + col0 + cc);
      Bs[kk][cc] = b.x; Bs[kk][cc + 1] = b.y; Bs[kk][cc + 2] = b.z; Bs[kk][cc + 3] = b.w;
    }
    __syncthreads();
#pragma unroll
    for (int kk = 0; kk < BK; ++kk) {
      float ar[8], br[4];
#pragma unroll
      for (int i = 0; i < 8; ++i) ar[i] = As[kk][ty * 8 + i];
#pragma unroll
      for (int j = 0; j < 4; ++j) br[j] = Bs[kk][tx * 4 + j];
#pragma unroll
      for (int i = 0; i < 8; ++i)
#pragma unroll
        for (int j = 0; j < 4; ++j) acc[i][j] += ar[i] * br[j];
    }
    __syncthreads();
  }
#pragma unroll
  for (int i = 0; i < 8; ++i) {
    int r = row0 + ty * 8 + i;
    if (r < M) {
      int c = col0 + tx * 4;
      float4 o;
      o.x = acc[i][0] + bias[c + 0];
      o.y = acc[i][1] + bias[c + 1];
      o.z = acc[i][2] + bias[c + 2];
      o.w = acc[i][3] + bias[c + 3];
      *(float4*)(C + (size_t)r * Nd + c) = o;
      ushort4 h;
      h.x = f2bf(o.x); h.y = f2bf(o.y); h.z = f2bf(o.z); h.w = f2bf(o.w);
      *(ushort4*)(C16 + (size_t)r * Nd + c) = h;
    }
  }
}

// ---------------- fused QKVS+Dq bf16 MFMA GEMM -----------------------------
// C[M x 1152] = A[M x 256] @ Bt^T  (Bt is [1152][256], k-contiguous)
__global__ __launch_bounds__(256) void k_qkvs(
    const ushort_t* __restrict__ A, const ushort_t* __restrict__ Bt,
    const float* __restrict__ bias, ushort_t* __restrict__ Qb16,
    ushort_t* __restrict__ KVb, ushort_t* __restrict__ Sb16,
    float* __restrict__ Dqb, int M) {
  __shared__ short lds_a[8192];   // 128 x 64 bf16 (swizzled granules)
  __shared__ short lds_b[8192];
  int t = threadIdx.x;
  int lane = t & 63, wv = t >> 6;
  int row0 = blockIdx.y * 128, col0 = blockIdx.x * 128;

  f32x4 acc[4][4];
#pragma unroll
  for (int im = 0; im < 4; ++im)
#pragma unroll
    for (int in = 0; in < 4; ++in) acc[im][in] = (f32x4){0.f, 0.f, 0.f, 0.f};

  int ln16 = lane & 15, q = lane >> 4;
  int mbase = (wv >> 1) * 64;
  int nbase = (wv & 1) * 64;

  for (int kk = 0; kk < 4; ++kk) {
    int k0 = kk * 64;
    __syncthreads();          // protect previous iteration's LDS reads
#pragma unroll
    for (int i = 0; i < 4; ++i) {
      int gi = i * 256 + t;
      int r = gi >> 3, c = (gi & 7) ^ (r & 7);
      int gr = row0 + r; if (gr > M - 1) gr = M - 1;
      gl_lds16(A + (size_t)gr * 256 + k0 + c * 8, &((int4*)lds_a)[gi]);
      gl_lds16(Bt + (size_t)(col0 + r) * 256 + k0 + c * 8, &((int4*)lds_b)[gi]);
    }
    __syncthreads();          // drains vmcnt(0) then barrier
#pragma unroll
    for (int kc = 0; kc < 2; ++kc) {
      s16x8 af[4], bf[4];
      int cq = kc * 4 + q;
#pragma unroll
      for (int im = 0; im < 4; ++im) {
        int r = mbase + im * 16 + ln16;
        af[im] = ((const s16x8*)lds_a)[r * 8 + (cq ^ (r & 7))];
      }
#pragma unroll
      for (int in = 0; in < 4; ++in) {
        int r = nbase + in * 16 + ln16;
        bf[in] = ((const s16x8*)lds_b)[r * 8 + (cq ^ (r & 7))];
      }
#pragma unroll
      for (int im = 0; im < 4; ++im)
#pragma unroll
        for (int in = 0; in < 4; ++in)
          acc[im][in] = __builtin_amdgcn_mfma_f32_16x16x32_bf16(af[im], bf[in], acc[im][in], 0, 0, 0);
    }
  }

  // epilogue: C[m = q*4+j][n = ln16] per tile.
#pragma unroll
  for (int in = 0; in < 4; ++in) {
    int ncol = col0 + nbase + in * 16 + ln16;
    int lc = ncol & 255;
    float bz = bias[ncol];
#pragma unroll
    for (int im = 0; im < 4; ++im) {
#pragma unroll
      for (int j = 0; j < 4; ++j) {
        int mr = row0 + mbase + im * 16 + q * 4 + j;
        if (mr < M) {
          float v = acc[im][in][j] + bz;
          if (ncol < 256)       Qb16[(size_t)mr * 256 + lc] = f2bf(v);
          else if (ncol < 512)  KVb[(size_t)mr * 512 + (lc >> 2) * 8 + (lc & 3)] = f2bf(v);
          else if (ncol < 768)  KVb[(size_t)mr * 512 + (lc >> 2) * 8 + (lc & 3) + 4] = f2bf(v);
          else if (ncol < 1024) Sb16[(size_t)mr * 256 + lc] = f2bf(v);
          else { int j2 = ncol - 1024; if (j2 < 68) Dqb[(size_t)mr * 68 + j2] = v; }
        }
      }
    }
  }
}

// ---------------- attention + beta-gate blend: one node per wave -----------
// Block-softmax: scores for a 4-edge group computed independently (ILP),
// ONE rescale of (dn, ac, wa) per group (exact flash-block math).
__global__ __launch_bounds__(256) void k_attn(
    const ushort_t* __restrict__ Qp, const ushort_t* __restrict__ KVm,
    const float* __restrict__ Dqp,
    const float* __restrict__ ea_g, const int* __restrict__ srcA,
    const float* __restrict__ We_l, const float* __restrict__ be_l,
    const float* __restrict__ Wb, const int* __restrict__ row_ptr,
    const int* __restrict__ csr, const ushort_t* __restrict__ Sp,
    float* __restrict__ xout, int nNodes) {
  __shared__ float sWb[768];
  int t = threadIdx.x;
  sWb[t] = Wb[t];
  sWb[t + 256] = Wb[t + 256];
  sWb[t + 512] = Wb[t + 512];
  __syncthreads();
  int lane = t & 63;
  int t16 = lane & 15;
  int n = blockIdx.x * 4 + (t >> 6);
  if (n >= nNodes) return;

  float4 be4 = *(const float4*)(be_l + 4 * lane);
  ushort4 qh = *(const ushort4*)(Qp + (size_t)n * 256 + 4 * lane);
  float4 qs = make_float4(bf2f(qh.x) * 0.125f, bf2f(qh.y) * 0.125f,
                          bf2f(qh.z) * 0.125f, bf2f(qh.w) * 0.125f);
  float dqv = Dqp[(size_t)n * 68 + lane];
  float qbe = Dqp[(size_t)n * 68 + 64 + (lane >> 4)];
  int beg = row_ptr[n], end = row_ptr[n + 1];

  float m = -INFINITY, dn = 0.f, wa = 0.f;
  float4 ac = make_float4(0.f, 0.f, 0.f, 0.f);

  for (int base = beg; base < end; base += 64) {
    int cnt = min(64, end - base);
    int eL = 0, sL = 0;
    if (lane < cnt) { eL = csr[base + lane]; sL = srcA[eL]; }

    u16x8 bufA[4], bufB[4];
    float eaA = 0.f, eaB = 0.f;

    auto ld4 = [&](u16x8* buf, float& eaR, int g4) {
      if (g4 >= cnt) return;
      int esel = g4 + (lane >> 4);              // <= 63 whenever g4 < cnt
      int eid = __shfl(eL, esel, 64);
      eaR = ea_g[(size_t)eid * 16 + t16];
#pragma unroll
      for (int jj = 0; jj < 4; ++jj) {
        if (g4 + jj < cnt) {
          int s = __shfl(sL, g4 + jj, 64);
          buf[jj] = *(const u16x8*)(KVm + (size_t)s * 512 + lane * 8);
        } else {
          buf[jj] = (u16x8)(0);
        }
      }
    };
    // block-softmax: 4 independent scores, one rescale per group
    auto proc4 = [&](const u16x8* buf, float eaR, int g4) {
      float p[4], eatv[4];
#pragma unroll
      for (int jj = 0; jj < 4; ++jj) {
        eatv[jj] = __shfl(eaR, (jj << 4) | t16, 64);
        float part = qs.x * bf2f(buf[jj][0]) + qs.y * bf2f(buf[jj][1]) +
                     qs.z * bf2f(buf[jj][2]) + qs.w * bf2f(buf[jj][3]) +
                     eatv[jj] * dqv;
        float pj = red16(part) + qbe;
        p[jj] = (g4 + jj < cnt) ? pj : -INFINITY;
      }
      float gm = fmaxf(fmaxf(p[0], p[1]), fmaxf(p[2], p[3]));
      float mn = fmaxf(m, gm);
      float scl = __expf(m - mn);   // first group: m=-inf -> 0
      m = mn;
      float w0 = __expf(p[0] - mn);   // -inf -> 0 for inactive
      float w1 = __expf(p[1] - mn);
      float w2 = __expf(p[2] - mn);
      float w3 = __expf(p[3] - mn);
      dn = dn * scl + ((w0 + w1) + (w2 + w3));
      ac.x = ac.x * scl + ((w0 * bf2f(buf[0][4]) + w1 * bf2f(buf[1][4])) +
                           (w2 * bf2f(buf[2][4]) + w3 * bf2f(buf[3][4])));
      ac.y = ac.y * scl + ((w0 * bf2f(buf[0][5]) + w1 * bf2f(buf[1][5])) +
                           (w2 * bf2f(buf[2][5]) + w3 * bf2f(buf[3][5])));
      ac.z = ac.z * scl + ((w0 * bf2f(buf[0][6]) + w1 * bf2f(buf[1][6])) +
                           (w2 * bf2f(buf[2][6]) + w3 * bf2f(buf[3][6])));
      ac.w = ac.w * scl + ((w0 * bf2f(buf[0][7]) + w1 * bf2f(buf[1][7])) +
                           (w2 * bf2f(buf[2][7]) + w3 * bf2f(buf[3][7])));
      wa = wa * scl + ((w0 * eatv[0] + w1 * eatv[1]) + (w2 * eatv[2] + w3 * eatv[3]));
    };

    ld4(bufA, eaA, 0);
    for (int g4 = 0; g4 < cnt; g4 += 8) {
      ld4(bufB, eaB, g4 + 4);
      proc4(bufA, eaA, g4);
      if (g4 + 4 >= cnt) break;
      ld4(bufA, eaA, g4 + 8);
      proc4(bufB, eaB, g4 + 4);
    }
  }

  // epilogue
  float4 o = make_float4(0.f, 0.f, 0.f, 0.f);
  float wacc = 0.f;
  if (end > beg) {
    float inv = 1.0f / dn;
    o.x = ac.x * inv + be4.x;
    o.y = ac.y * inv + be4.y;
    o.z = ac.z * inv + be4.z;
    o.w = ac.w * inv + be4.w;
    wacc = wa * inv;
  }
  int lanebase = lane & 48;
#pragma unroll
  for (int tt = 0; tt < 16; ++tt) {
    float4 w4 = *(const float4*)(We_l + tt * 256 + 4 * lane);
    float wv = __shfl(wacc, lanebase + tt, 64);
    o.x += wv * w4.x; o.y += wv * w4.y; o.z += wv * w4.z; o.w += wv * w4.w;
  }

  // fused beta-gate blend
  ushort4 rh = *(const ushort4*)(Sp + (size_t)n * 256 + 4 * lane);
  float4 r = make_float4(bf2f(rh.x), bf2f(rh.y), bf2f(rh.z), bf2f(rh.w));
  int c = 4 * lane;
  float z = o.x * sWb[c] + o.y * sWb[c + 1] + o.z * sWb[c + 2] + o.w * sWb[c + 3]
          + r.x * sWb[256 + c] + r.y * sWb[257 + c] + r.z * sWb[258 + c] + r.w * sWb[259 + c]
          + (o.x - r.x) * sWb[512 + c] + (o.y - r.y) * sWb[513 + c]
          + (o.z - r.z) * sWb[514 + c] + (o.w - r.w) * sWb[515 + c];
#pragma unroll
  for (int off = 1; off < 64; off <<= 1) z += __shfl_xor(z, off, 64);
  float beta = 1.0f / (1.0f + __expf(-z));
  float4 xn;
  xn.x = beta * r.x + (1.f - beta) * o.x;
  xn.y = beta * r.y + (1.f - beta) * o.y;
  xn.z = beta * r.z + (1.f - beta) * o.z;
  xn.w = beta * r.w + (1.f - beta) * o.w;
  *(float4*)(xout + (size_t)n * 256 + 4 * lane) = xn;
}

// ---------------- batchnorm ------------------------------------------------
__global__ void k_bnstats(const float* __restrict__ x, float* __restrict__ sums,
                          float* __restrict__ sums2, int nRows) {
  int c = threadIdx.x;
  int rpb = (nRows + gridDim.x - 1) / gridDim.x;
  int r0 = blockIdx.x * rpb;
  int r1 = min(nRows, r0 + rpb);
  float s = 0.f, s2 = 0.f;
  for (int r = r0; r < r1; ++r) {
    float v = x[(size_t)r * 256 + c];
    s += v;
    s2 += v * v;
  }
  atomicAdd(&sums[c], s);
  atomicAdd(&sums2[c], s2);
}

__global__ __launch_bounds__(256) void k_bnapply(
    float* __restrict__ x, ushort_t* __restrict__ x16,
    const float* __restrict__ sums, const float* __restrict__ sums2,
    const float* __restrict__ gamma, const float* __restrict__ betap, int nRows) {
  int total4 = nRows * 64;
  float invN = 1.0f / (float)nRows;
  for (int i4 = blockIdx.x * 256 + threadIdx.x; i4 < total4; i4 += gridDim.x * 256) {
    int c4 = (i4 & 63) * 4;
    float4 xv = *(const float4*)(x + (size_t)i4 * 4);
    float4 s = *(const float4*)(sums + c4);
    float4 s2 = *(const float4*)(sums2 + c4);
    float4 g = *(const float4*)(gamma + c4);
    float4 b = *(const float4*)(betap + c4);
    float mu0 = s.x * invN, mu1 = s.y * invN, mu2 = s.z * invN, mu3 = s.w * invN;
    float sc0 = rsqrtf(s2.x * invN - mu0 * mu0 + EPS) * g.x;
    float sc1 = rsqrtf(s2.y * invN - mu1 * mu1 + EPS) * g.y;
    float sc2 = rsqrtf(s2.z * invN - mu2 * mu2 + EPS) * g.z;
    float sc3 = rsqrtf(s2.w * invN - mu3 * mu3 + EPS) * g.w;
    float4 v;
    v.x = (xv.x - mu0) * sc0 + b.x;
    v.y = (xv.y - mu1) * sc1 + b.y;
    v.z = (xv.z - mu2) * sc2 + b.z;
    v.w = (xv.w - mu3) * sc3 + b.w;
    v.x = v.x >= 0.f ? v.x : 0.1f * v.x;
    v.y = v.y >= 0.f ? v.y : 0.1f * v.y;
    v.z = v.z >= 0.f ? v.z : 0.1f * v.z;
    v.w = v.w >= 0.f ? v.w : 0.1f * v.w;
    *(float4*)(x + (size_t)i4 * 4) = v;
    ushort4 h;
    h.x = f2bf(v.x); h.y = f2bf(v.y); h.z = f2bf(v.z); h.w = f2bf(v.w);
    *(ushort4*)(x16 + (size_t)i4 * 4) = h;
  }
}

// ---------------- pooling + head -------------------------------------------
__global__ void k_pool(const float* __restrict__ x, const int* __restrict__ batch,
                       float* __restrict__ pool, int nRows) {
  int c = threadIdx.x;
  int rpb = (nRows + gridDim.x - 1) / gridDim.x;
  int r0 = blockIdx.x * rpb;
  int r1 = min(nRows, r0 + rpb);
  float acc = 0.f;
  int gc = -1;
  for (int r = r0; r < r1; ++r) {
    int g = batch[r];
    if (g != gc) {
      if (gc >= 0) atomicAdd(&pool[gc * 256 + c], acc);
      acc = 0.f;
      gc = g;
    }
    acc += x[(size_t)r * 256 + c];
  }
  if (gc >= 0) atomicAdd(&pool[gc * 256 + c], acc);
}

// head with inline per-graph counts (batch sorted -> binary search)
__global__ void k_head(const float* __restrict__ pool, const int* __restrict__ batch,
                       const float* __restrict__ hW, const float* __restrict__ hb,
                       float* __restrict__ outp, int nRows) {
  int g = blockIdx.x, lane = threadIdx.x;
  int lo = 0, hi = nRows;
  while (lo < hi) { int mid = (lo + hi) >> 1; if (batch[mid] < g) lo = mid + 1; else hi = mid; }
  int lb = lo;
  lo = 0; hi = nRows;
  while (lo < hi) { int mid = (lo + hi) >> 1; if (batch[mid] < g + 1) lo = mid + 1; else hi = mid; }
  float cnt = fmaxf((float)(lo - lb), 1.0f);
  float z = 0.f;
#pragma unroll
  for (int i = 0; i < 4; ++i) {
    int c = lane + i * 64;
    float s = pool[g * 256 + c];
    z += (s / cnt) * hW[c] + s * hW[256 + c];
  }
#pragma unroll
  for (int off = 1; off < 64; off <<= 1) z += __shfl_xor(z, off, 64);
  if (lane == 0) outp[g] = z + hb[0];
}

// ---------------------------------------------------------------------------
extern "C" void kernel_launch(void* const* d_in, const int* in_sizes, int n_in,
                              void* d_out, int out_size, void* d_ws, size_t ws_size,
                              hipStream_t stream) {
  const float* node_features = (const float*)d_in[0];
  const int*   edge_index    = (const int*)d_in[1];
  const float* edge_attr     = (const float*)d_in[2];
  const int*   batch         = (const int*)d_in[3];
  const float* proj_W  = (const float*)d_in[4];
  const float* proj_b  = (const float*)d_in[5];
  const float* Wq      = (const float*)d_in[6];
  const float* bq      = (const float*)d_in[7];
  const float* Wk      = (const float*)d_in[8];
  const float* bk      = (const float*)d_in[9];
  const float* Wv      = (const float*)d_in[10];
  const float* bv      = (const float*)d_in[11];
  const float* We      = (const float*)d_in[12];
  const float* be      = (const float*)d_in[13];
  const float* Wskip   = (const float*)d_in[14];
  const float* bskip   = (const float*)d_in[15];
  const float* Wbeta   = (const float*)d_in[16];
  const float* bn_gamma= (const float*)d_in[17];
  const float* bn_beta = (const float*)d_in[18];
  const float* head_W  = (const float*)d_in[19];
  const float* head_b  = (const float*)d_in[20];
  float* out_dev = (float*)d_out;

  const int Nn = in_sizes[0] / 64;   // 50000
  const int Ee = in_sizes[1] / 2;    // 500000
  const int Gg = out_size;           // 64

  char* ws = (char*)d_ws;
  size_t off = 0;
  auto alloc = [&](size_t bytes) -> void* {
    void* p = ws + off;
    off += (bytes + 255) & ~(size_t)255;
    return p;
  };
  float*    xb     = (float*)alloc((size_t)Nn * 256 * 4);
  float*    Dqb    = (float*)alloc((size_t)Nn * 68 * 4);
  ushort_t* Qb16   = (ushort_t*)alloc((size_t)Nn * 256 * 2);
  ushort_t* Sb16   = (ushort_t*)alloc((size_t)Nn * 256 * 2);
  ushort_t* KVb    = (ushort_t*)alloc((size_t)Nn * 512 * 2);   // interleaved K|V
  ushort_t* xb16   = (ushort_t*)alloc((size_t)Nn * 256 * 2);
  ushort_t* Wcat_t = (ushort_t*)alloc((size_t)4 * 1152 * 256 * 2);
  float*    bias_cat = (float*)alloc((size_t)4 * 1152 * 4);
  float*    bnstat = (float*)alloc(512 * 4);
  float*    pool   = (float*)alloc((size_t)Gg * 256 * 4);
  int* deg     = (int*)alloc((size_t)Nn * 4);
  int* fill    = (int*)alloc((size_t)Nn * 4);
  int* row_ptr = (int*)alloc((size_t)(Nn + 1) * 4);
  int* csr     = (int*)alloc((size_t)Ee * 4);
  (void)ws_size; (void)n_in;

  const int* srcA = edge_index;
  const int* dstA = edge_index + Ee;

  // CSR build by dst
  hipMemsetAsync(deg, 0, (size_t)Nn * 4, stream);
  hipMemsetAsync(fill, 0, (size_t)Nn * 4, stream);
  k_count<<<(Ee + 255) / 256, 256, 0, stream>>>(dstA, deg, Ee);
  k_scan<<<1, 1024, 0, stream>>>(deg, row_ptr, Nn);
  k_scatter<<<(Ee + 255) / 256, 256, 0, stream>>>(dstA, row_ptr, fill, csr, Ee);

  // weight/bias conversion (bf16, transposed concat) + composite dq rows
  k_wconv<<<dim3(8, 8, 16), dim3(32, 8), 0, stream>>>(Wq, Wk, Wv, Wskip, Wcat_t);
  k_bconv<<<16, 256, 0, stream>>>(bq, bk, bv, bskip, bias_cat);
  k_mkdq<<<dim3(68, 4), 256, 0, stream>>>(Wq, bq, We, be, Wcat_t, bias_cat);

  // input projection (fp32) + bf16 mirror
  dim3 gemm_grid(256 / BN, (Nn + BM - 1) / BM);
  k_gemm<<<gemm_grid, 256, 0, stream>>>(node_features, proj_W, proj_b, xb, xb16, Nn, 64, 256);

  int nodeBlocks = (Nn + 3) / 4;
  dim3 qkvs_grid(9, (Nn + 127) / 128);
  for (int l = 0; l < 4; ++l) {
    k_qkvs<<<qkvs_grid, 256, 0, stream>>>(xb16, Wcat_t + (size_t)l * (1152 * 256),
                                          bias_cat + l * 1152, Qb16, KVb, Sb16, Dqb, Nn);

    k_attn<<<nodeBlocks, 256, 0, stream>>>(Qb16, KVb, Dqb, edge_attr, srcA,
                                           We + (size_t)l * 4096, be + l * 256,
                                           Wbeta + (size_t)l * 768,
                                           row_ptr, csr, Sb16, xb, Nn);

    hipMemsetAsync(bnstat, 0, 512 * 4, stream);
    k_bnstats<<<512, 256, 0, stream>>>(xb, bnstat, bnstat + 256, Nn);
    k_bnapply<<<512, 256, 0, stream>>>(xb, xb16, bnstat, bnstat + 256,
                                       bn_gamma + l * 256, bn_beta + l * 256, Nn);
  }

  hipMemsetAsync(pool, 0, (size_t)Gg * 256 * 4, stream);
  k_pool<<<256, 256, 0, stream>>>(xb, batch, pool, Nn);
  k_head<<<Gg, 64, 0, stream>>>(pool, batch, head_W, head_b, out_dev, Nn);
}

// Round 9
// 1357.207 us; speedup vs baseline: 9.5875x; 1.0263x over previous
//
#include <hip/hip_runtime.h>
#include <math.h>

// ---------------------------------------------------------------------------
// AnticipatoryRestaurantGNN round 9:
//  - k_attn: 16-lane score reduction via DPP row_ror rotate-add (pure VALU,
//    replaces 4 dependent ds_bpermute per edge), edge-attr via direct 4B
//    per-lane loads (readlane-broadcast edge id) -> zero LDS-pipe cross-lane
//    ops in the hot loop.
//  - x is bf16 end-to-end: attn writes bf16, bnstats/bnapply(in-place)/pool
//    read bf16; fp32 x buffer eliminated (~125 MB/layer less traffic).
// ---------------------------------------------------------------------------

#define EPS 1e-5f
typedef unsigned short ushort_t;
typedef unsigned int uint_t;

using f32x4 = __attribute__((ext_vector_type(4))) float;
using s16x8 = __attribute__((ext_vector_type(8))) short;
using u16x8 = __attribute__((ext_vector_type(8))) unsigned short;

__device__ __forceinline__ ushort_t f2bf(float f) {
  union { float f; uint_t u; } v; v.f = f;
  uint_t u = v.u;
  uint_t r = (u + 0x7FFFu + ((u >> 16) & 1u)) >> 16;   // RNE
  return (ushort_t)r;
}
__device__ __forceinline__ float bf2f(ushort_t h) {
  union { uint_t u; float f; } v; v.u = ((uint_t)h) << 16;
  return v.f;
}

__device__ __forceinline__ void gl_lds16(const void* g, void* l) {
  __builtin_amdgcn_global_load_lds(
      (const __attribute__((address_space(1))) void*)g,
      (__attribute__((address_space(3))) void*)l, 16, 0, 0);
}

// DPP rotate-add reduction over each 16-lane row (per-head), pure VALU.
template <int CTRL>
__device__ __forceinline__ float dpp_add(float x) {
  int v = __builtin_amdgcn_update_dpp(0, __float_as_int(x), CTRL, 0xF, 0xF, true);
  return x + __int_as_float(v);
}
__device__ __forceinline__ float red16_dpp(float x) {
  x = dpp_add<0x121>(x);   // row_ror:1
  x = dpp_add<0x122>(x);   // row_ror:2
  x = dpp_add<0x124>(x);   // row_ror:4
  x = dpp_add<0x128>(x);   // row_ror:8
  return x;
}

// ---------------- CSR build (by dst; dst reused across all 4 layers) -------
__global__ void k_count(const int* __restrict__ dst, int* __restrict__ deg, int n) {
  int i = blockIdx.x * 256 + threadIdx.x;
  if (i < n) atomicAdd(&deg[dst[i]], 1);
}

__global__ void k_scan(const int* __restrict__ deg, int* __restrict__ row_ptr, int n) {
  __shared__ int wsum[16];
  __shared__ int carry_s;
  int t = threadIdx.x, lane = t & 63, w = t >> 6;
  if (t == 0) { carry_s = 0; row_ptr[0] = 0; }
  __syncthreads();
  for (int base = 0; base < n; base += 1024) {
    int v = (base + t < n) ? deg[base + t] : 0;
    int x = v;
#pragma unroll
    for (int off = 1; off < 64; off <<= 1) {
      int y = __shfl_up(x, off, 64);
      if (lane >= off) x += y;
    }
    if (lane == 63) wsum[w] = x;
    __syncthreads();
    if (w == 0 && lane < 16) {
      int s = wsum[lane];
#pragma unroll
      for (int off = 1; off < 16; off <<= 1) {
        int y = __shfl_up(s, off, 64);
        if (lane >= off) s += y;
      }
      wsum[lane] = s;
    }
    __syncthreads();
    int add = (w > 0) ? wsum[w - 1] : 0;
    int incl = x + add + carry_s;
    if (base + t < n) row_ptr[base + t + 1] = incl;
    __syncthreads();
    if (t == 1023) carry_s = incl;
    __syncthreads();
  }
}

__global__ void k_scatter(const int* __restrict__ dst, const int* __restrict__ row_ptr,
                          int* __restrict__ fill, int* __restrict__ csr, int n) {
  int i = blockIdx.x * 256 + threadIdx.x;
  if (i < n) {
    int d = dst[i];
    int pos = atomicAdd(&fill[d], 1);
    csr[row_ptr[d] + pos] = i;
  }
}

// ---------------- weight convert: Wcat_t[l][n=1152][k=256] bf16 ------------
__global__ void k_wconv(const float* __restrict__ Wq, const float* __restrict__ Wk,
                        const float* __restrict__ Wv, const float* __restrict__ Ws,
                        ushort_t* __restrict__ Wcat_t) {
  __shared__ float tile[32][33];
  int l = blockIdx.z >> 2, sel = blockIdx.z & 3;
  const float* W = (sel == 0) ? Wq : (sel == 1) ? Wk : (sel == 2) ? Wv : Ws;
  W += (size_t)l * 65536;
  int k0 = blockIdx.x * 32, n0 = blockIdx.y * 32;
  int tx = threadIdx.x, ty = threadIdx.y;           // 32 x 8
#pragma unroll
  for (int i = 0; i < 32; i += 8) tile[ty + i][tx] = W[(size_t)(k0 + ty + i) * 256 + n0 + tx];
  __syncthreads();
  ushort_t* dst = Wcat_t + (size_t)l * (1152 * 256) + (size_t)(sel * 256 + n0) * 256 + k0;
#pragma unroll
  for (int i = 0; i < 32; i += 8) dst[(size_t)(ty + i) * 256 + tx] = f2bf(tile[tx][ty + i]);
}

// composite rows 1024..1091: M[ci][j] = sum_{c in head(j)} Wq[ci][c]*w2[c]
__global__ void k_mkdq(const float* __restrict__ Wq, const float* __restrict__ bq,
                       const float* __restrict__ We, const float* __restrict__ be,
                       ushort_t* __restrict__ Wcat_t, float* __restrict__ bias_cat) {
  int j = blockIdx.x;        // 0..67
  int l = blockIdx.y;        // 0..3
  int ci = threadIdx.x;      // 0..255
  __shared__ float w2[64];
  int h = (j < 64) ? (j >> 4) : (j - 64);
  if (ci < 64) {
    float v;
    if (j < 64) v = We[(size_t)l * 4096 + (j & 15) * 256 + h * 64 + ci];
    else        v = be[l * 256 + h * 64 + ci];
    w2[ci] = v * 0.125f;
  }
  __syncthreads();
  const float* Wq_l = Wq + (size_t)l * 65536;
  float acc = 0.f;
#pragma unroll 8
  for (int c = 0; c < 64; ++c) acc += Wq_l[(size_t)ci * 256 + h * 64 + c] * w2[c];
  Wcat_t[(size_t)l * (1152 * 256) + (size_t)(1024 + j) * 256 + ci] = f2bf(acc);
  if (ci == 0) {
    const float* bq_l = bq + l * 256;
    float d0 = 0.f;
    for (int c = 0; c < 64; ++c) d0 += bq_l[h * 64 + c] * w2[c];
    bias_cat[l * 1152 + 1024 + j] = d0;
  }
}

__global__ void k_bconv(const float* __restrict__ bq, const float* __restrict__ bk,
                        const float* __restrict__ bv, const float* __restrict__ bs,
                        float* __restrict__ bias_cat) {
  int idx = blockIdx.x * 256 + threadIdx.x;   // 4096 total
  if (idx >= 4096) return;
  int l = idx >> 10, rest = idx & 1023, sel = rest >> 8, c = rest & 255;
  const float* p = (sel == 0) ? bq : (sel == 1) ? bk : (sel == 2) ? bv : bs;
  bias_cat[l * 1152 + rest] = p[l * 256 + c];
}

// ---------------- fp32 tiled GEMM (input projection only, bf16 out) --------
#define BM 128
#define BN 64
#define BK 16
__global__ __launch_bounds__(256) void k_gemm(
    const float* __restrict__ A, const float* __restrict__ B,
    const float* __restrict__ bias, ushort_t* __restrict__ C16,
    int M, int Kd, int Nd) {
  __shared__ float As[BK][BM + 4];
  __shared__ float Bs[BK][BN + 4];
  int t = threadIdx.x;
  int tx = t & 15, ty = t >> 4;
  int row0 = blockIdx.y * BM, col0 = blockIdx.x * BN;
  float acc[8][4] = {};
  for (int k0 = 0; k0 < Kd; k0 += BK) {
#pragma unroll
    for (int i = 0; i < 2; ++i) {
      int idx = t + i * 256;
      int r = idx >> 2, kk = (idx & 3) * 4;
      float4 a = make_float4(0.f, 0.f, 0.f, 0.f);
      if (row0 + r < M) a = *(const float4*)(A + (size_t)(row0 + r) * Kd + k0 + kk);
      As[kk + 0][r] = a.x; As[kk + 1][r] = a.y; As[kk + 2][r] = a.z; As[kk + 3][r] = a.w;
    }
    {
      int kk = t >> 4, cc = (t & 15) * 4;
      float4 b = *(const float4*)(B + (size_t)(k0 + kk) * Nd + col0 + cc);
      Bs[kk][cc] = b.x; Bs[kk][cc + 1] = b.y; Bs[kk][cc + 2] = b.z; Bs[kk][cc + 3] = b.w;
    }
    __syncthreads();
#pragma unroll
    for (int kk = 0; kk < BK; ++kk) {
      float ar[8], br[4];
#pragma unroll
      for (int i = 0; i < 8; ++i) ar[i] = As[kk][ty * 8 + i];
#pragma unroll
      for (int j = 0; j < 4; ++j) br[j] = Bs[kk][tx * 4 + j];
#pragma unroll
      for (int i = 0; i < 8; ++i)
#pragma unroll
        for (int j = 0; j < 4; ++j) acc[i][j] += ar[i] * br[j];
    }
    __syncthreads();
  }
#pragma unroll
  for (int i = 0; i < 8; ++i) {
    int r = row0 + ty * 8 + i;
    if (r < M) {
      int c = col0 + tx * 4;
      ushort4 h;
      h.x = f2bf(acc[i][0] + bias[c + 0]);
      h.y = f2bf(acc[i][1] + bias[c + 1]);
      h.z = f2bf(acc[i][2] + bias[c + 2]);
      h.w = f2bf(acc[i][3] + bias[c + 3]);
      *(ushort4*)(C16 + (size_t)r * Nd + c) = h;
    }
  }
}

// ---------------- fused QKVS+Dq bf16 MFMA GEMM -----------------------------
// C[M x 1152] = A[M x 256] @ Bt^T  (Bt is [1152][256], k-contiguous)
__global__ __launch_bounds__(256) void k_qkvs(
    const ushort_t* __restrict__ A, const ushort_t* __restrict__ Bt,
    const float* __restrict__ bias, ushort_t* __restrict__ Qb16,
    ushort_t* __restrict__ KVb, ushort_t* __restrict__ Sb16,
    float* __restrict__ Dqb, int M) {
  __shared__ short lds_a[8192];   // 128 x 64 bf16 (swizzled granules)
  __shared__ short lds_b[8192];
  int t = threadIdx.x;
  int lane = t & 63, wv = t >> 6;
  int row0 = blockIdx.y * 128, col0 = blockIdx.x * 128;

  f32x4 acc[4][4];
#pragma unroll
  for (int im = 0; im < 4; ++im)
#pragma unroll
    for (int in = 0; in < 4; ++in) acc[im][in] = (f32x4){0.f, 0.f, 0.f, 0.f};

  int ln16 = lane & 15, q = lane >> 4;
  int mbase = (wv >> 1) * 64;
  int nbase = (wv & 1) * 64;

  for (int kk = 0; kk < 4; ++kk) {
    int k0 = kk * 64;
    __syncthreads();          // protect previous iteration's LDS reads
#pragma unroll
    for (int i = 0; i < 4; ++i) {
      int gi = i * 256 + t;
      int r = gi >> 3, c = (gi & 7) ^ (r & 7);
      int gr = row0 + r; if (gr > M - 1) gr = M - 1;
      gl_lds16(A + (size_t)gr * 256 + k0 + c * 8, &((int4*)lds_a)[gi]);
      gl_lds16(Bt + (size_t)(col0 + r) * 256 + k0 + c * 8, &((int4*)lds_b)[gi]);
    }
    __syncthreads();          // drains vmcnt(0) then barrier
#pragma unroll
    for (int kc = 0; kc < 2; ++kc) {
      s16x8 af[4], bf[4];
      int cq = kc * 4 + q;
#pragma unroll
      for (int im = 0; im < 4; ++im) {
        int r = mbase + im * 16 + ln16;
        af[im] = ((const s16x8*)lds_a)[r * 8 + (cq ^ (r & 7))];
      }
#pragma unroll
      for (int in = 0; in < 4; ++in) {
        int r = nbase + in * 16 + ln16;
        bf[in] = ((const s16x8*)lds_b)[r * 8 + (cq ^ (r & 7))];
      }
#pragma unroll
      for (int im = 0; im < 4; ++im)
#pragma unroll
        for (int in = 0; in < 4; ++in)
          acc[im][in] = __builtin_amdgcn_mfma_f32_16x16x32_bf16(af[im], bf[in], acc[im][in], 0, 0, 0);
    }
  }

  // epilogue: C[m = q*4+j][n = ln16] per tile.
#pragma unroll
  for (int in = 0; in < 4; ++in) {
    int ncol = col0 + nbase + in * 16 + ln16;
    int lc = ncol & 255;
    float bz = bias[ncol];
#pragma unroll
    for (int im = 0; im < 4; ++im) {
#pragma unroll
      for (int j = 0; j < 4; ++j) {
        int mr = row0 + mbase + im * 16 + q * 4 + j;
        if (mr < M) {
          float v = acc[im][in][j] + bz;
          if (ncol < 256)       Qb16[(size_t)mr * 256 + lc] = f2bf(v);
          else if (ncol < 512)  KVb[(size_t)mr * 512 + (lc >> 2) * 8 + (lc & 3)] = f2bf(v);
          else if (ncol < 768)  KVb[(size_t)mr * 512 + (lc >> 2) * 8 + (lc & 3) + 4] = f2bf(v);
          else if (ncol < 1024) Sb16[(size_t)mr * 256 + lc] = f2bf(v);
          else { int j2 = ncol - 1024; if (j2 < 68) Dqb[(size_t)mr * 68 + j2] = v; }
        }
      }
    }
  }
}

// ---------------- attention + beta-gate blend: one node per wave -----------
// Block-softmax (one rescale / 4-edge group), DPP row reduction, direct
// per-lane edge-attr loads.  Output written as bf16.
__global__ __launch_bounds__(256) void k_attn(
    const ushort_t* __restrict__ Qp, const ushort_t* __restrict__ KVm,
    const float* __restrict__ Dqp,
    const float* __restrict__ ea_g, const int* __restrict__ srcA,
    const float* __restrict__ We_l, const float* __restrict__ be_l,
    const float* __restrict__ Wb, const int* __restrict__ row_ptr,
    const int* __restrict__ csr, const ushort_t* __restrict__ Sp,
    ushort_t* __restrict__ xout, int nNodes) {
  __shared__ float sWb[768];
  int t = threadIdx.x;
  sWb[t] = Wb[t];
  sWb[t + 256] = Wb[t + 256];
  sWb[t + 512] = Wb[t + 512];
  __syncthreads();
  int lane = t & 63;
  int t16 = lane & 15;
  int n = blockIdx.x * 4 + (t >> 6);
  if (n >= nNodes) return;

  float4 be4 = *(const float4*)(be_l + 4 * lane);
  ushort4 qh = *(const ushort4*)(Qp + (size_t)n * 256 + 4 * lane);
  float4 qs = make_float4(bf2f(qh.x) * 0.125f, bf2f(qh.y) * 0.125f,
                          bf2f(qh.z) * 0.125f, bf2f(qh.w) * 0.125f);
  float dqv = Dqp[(size_t)n * 68 + lane];
  float qbe = Dqp[(size_t)n * 68 + 64 + (lane >> 4)];
  int beg = row_ptr[n], end = row_ptr[n + 1];

  float m = -INFINITY, dn = 0.f, wa = 0.f;
  float4 ac = make_float4(0.f, 0.f, 0.f, 0.f);

  for (int base = beg; base < end; base += 64) {
    int cnt = min(64, end - base);
    int eL = 0, sL = 0;
    if (lane < cnt) { eL = csr[base + lane]; sL = srcA[eL]; }

    u16x8 bufA[4], bufB[4];
    float eatA[4], eatB[4];

    // edge id / src broadcast is wave-uniform (v_readlane); every lane loads
    // its own 4B edge-attr component -> no LDS-pipe cross-lane ops.
    auto ld4 = [&](u16x8* buf, float* eat, int g4) {
      if (g4 >= cnt) return;
#pragma unroll
      for (int jj = 0; jj < 4; ++jj) {
        if (g4 + jj < cnt) {
          int e = __shfl(eL, g4 + jj, 64);
          int s = __shfl(sL, g4 + jj, 64);
          eat[jj] = ea_g[(size_t)e * 16 + t16];
          buf[jj] = *(const u16x8*)(KVm + (size_t)s * 512 + lane * 8);
        } else {
          buf[jj] = (u16x8)(0);
          eat[jj] = 0.f;
        }
      }
    };
    // block-softmax: 4 independent scores (DPP reduce), one rescale per group
    auto proc4 = [&](const u16x8* buf, const float* eat, int g4) {
      float p[4];
#pragma unroll
      for (int jj = 0; jj < 4; ++jj) {
        float part = qs.x * bf2f(buf[jj][0]) + qs.y * bf2f(buf[jj][1]) +
                     qs.z * bf2f(buf[jj][2]) + qs.w * bf2f(buf[jj][3]) +
                     eat[jj] * dqv;
        float pj = red16_dpp(part) + qbe;
        p[jj] = (g4 + jj < cnt) ? pj : -INFINITY;
      }
      float gm = fmaxf(fmaxf(p[0], p[1]), fmaxf(p[2], p[3]));
      float mn = fmaxf(m, gm);
      float scl = __expf(m - mn);   // first group: m=-inf -> 0
      m = mn;
      float w0 = __expf(p[0] - mn);   // -inf -> 0 for inactive
      float w1 = __expf(p[1] - mn);
      float w2 = __expf(p[2] - mn);
      float w3 = __expf(p[3] - mn);
      dn = dn * scl + ((w0 + w1) + (w2 + w3));
      ac.x = ac.x * scl + ((w0 * bf2f(buf[0][4]) + w1 * bf2f(buf[1][4])) +
                           (w2 * bf2f(buf[2][4]) + w3 * bf2f(buf[3][4])));
      ac.y = ac.y * scl + ((w0 * bf2f(buf[0][5]) + w1 * bf2f(buf[1][5])) +
                           (w2 * bf2f(buf[2][5]) + w3 * bf2f(buf[3][5])));
      ac.z = ac.z * scl + ((w0 * bf2f(buf[0][6]) + w1 * bf2f(buf[1][6])) +
                           (w2 * bf2f(buf[2][6]) + w3 * bf2f(buf[3][6])));
      ac.w = ac.w * scl + ((w0 * bf2f(buf[0][7]) + w1 * bf2f(buf[1][7])) +
                           (w2 * bf2f(buf[2][7]) + w3 * bf2f(buf[3][7])));
      wa = wa * scl + ((w0 * eat[0] + w1 * eat[1]) + (w2 * eat[2] + w3 * eat[3]));
    };

    ld4(bufA, eatA, 0);
    for (int g4 = 0; g4 < cnt; g4 += 8) {
      ld4(bufB, eatB, g4 + 4);
      proc4(bufA, eatA, g4);
      if (g4 + 4 >= cnt) break;
      ld4(bufA, eatA, g4 + 8);
      proc4(bufB, eatB, g4 + 4);
    }
  }

  // epilogue
  float4 o = make_float4(0.f, 0.f, 0.f, 0.f);
  float wacc = 0.f;
  if (end > beg) {
    float inv = 1.0f / dn;
    o.x = ac.x * inv + be4.x;
    o.y = ac.y * inv + be4.y;
    o.z = ac.z * inv + be4.z;
    o.w = ac.w * inv + be4.w;
    wacc = wa * inv;
  }
  int lanebase = lane & 48;
#pragma unroll
  for (int tt = 0; tt < 16; ++tt) {
    float4 w4 = *(const float4*)(We_l + tt * 256 + 4 * lane);
    float wv = __shfl(wacc, lanebase + tt, 64);
    o.x += wv * w4.x; o.y += wv * w4.y; o.z += wv * w4.z; o.w += wv * w4.w;
  }

  // fused beta-gate blend
  ushort4 rh = *(const ushort4*)(Sp + (size_t)n * 256 + 4 * lane);
  float4 r = make_float4(bf2f(rh.x), bf2f(rh.y), bf2f(rh.z), bf2f(rh.w));
  int c = 4 * lane;
  float z = o.x * sWb[c] + o.y * sWb[c + 1] + o.z * sWb[c + 2] + o.w * sWb[c + 3]
          + r.x * sWb[256 + c] + r.y * sWb[257 + c] + r.z * sWb[258 + c] + r.w * sWb[259 + c]
          + (o.x - r.x) * sWb[512 + c] + (o.y - r.y) * sWb[513 + c]
          + (o.z - r.z) * sWb[514 + c] + (o.w - r.w) * sWb[515 + c];
#pragma unroll
  for (int off = 1; off < 64; off <<= 1) z += __shfl_xor(z, off, 64);
  float beta = 1.0f / (1.0f + __expf(-z));
  ushort4 xh;
  xh.x = f2bf(beta * r.x + (1.f - beta) * o.x);
  xh.y = f2bf(beta * r.y + (1.f - beta) * o.y);
  xh.z = f2bf(beta * r.z + (1.f - beta) * o.z);
  xh.w = f2bf(beta * r.w + (1.f - beta) * o.w);
  *(ushort4*)(xout + (size_t)n * 256 + 4 * lane) = xh;
}

// ---------------- batchnorm (bf16 x, in-place) -----------------------------
__global__ void k_bnstats(const ushort_t* __restrict__ x16, float* __restrict__ sums,
                          float* __restrict__ sums2, int nRows) {
  int c = threadIdx.x;
  int rpb = (nRows + gridDim.x - 1) / gridDim.x;
  int r0 = blockIdx.x * rpb;
  int r1 = min(nRows, r0 + rpb);
  float s = 0.f, s2 = 0.f;
  for (int r = r0; r < r1; ++r) {
    float v = bf2f(x16[(size_t)r * 256 + c]);
    s += v;
    s2 += v * v;
  }
  atomicAdd(&sums[c], s);
  atomicAdd(&sums2[c], s2);
}

__global__ __launch_bounds__(256) void k_bnapply(
    ushort_t* __restrict__ x16,
    const float* __restrict__ sums, const float* __restrict__ sums2,
    const float* __restrict__ gamma, const float* __restrict__ betap, int nRows) {
  int total4 = nRows * 64;
  float invN = 1.0f / (float)nRows;
  for (int i4 = blockIdx.x * 256 + threadIdx.x; i4 < total4; i4 += gridDim.x * 256) {
    int c4 = (i4 & 63) * 4;
    ushort4 xh = *(const ushort4*)(x16 + (size_t)i4 * 4);
    float4 s = *(const float4*)(sums + c4);
    float4 s2 = *(const float4*)(sums2 + c4);
    float4 g = *(const float4*)(gamma + c4);
    float4 b = *(const float4*)(betap + c4);
    float mu0 = s.x * invN, mu1 = s.y * invN, mu2 = s.z * invN, mu3 = s.w * invN;
    float sc0 = rsqrtf(s2.x * invN - mu0 * mu0 + EPS) * g.x;
    float sc1 = rsqrtf(s2.y * invN - mu1 * mu1 + EPS) * g.y;
    float sc2 = rsqrtf(s2.z * invN - mu2 * mu2 + EPS) * g.z;
    float sc3 = rsqrtf(s2.w * invN - mu3 * mu3 + EPS) * g.w;
    float v0 = (bf2f(xh.x) - mu0) * sc0 + b.x;
    float v1 = (bf2f(xh.y) - mu1) * sc1 + b.y;
    float v2 = (bf2f(xh.z) - mu2) * sc2 + b.z;
    float v3 = (bf2f(xh.w) - mu3) * sc3 + b.w;
    v0 = v0 >= 0.f ? v0 : 0.1f * v0;
    v1 = v1 >= 0.f ? v1 : 0.1f * v1;
    v2 = v2 >= 0.f ? v2 : 0.1f * v2;
    v3 = v3 >= 0.f ? v3 : 0.1f * v3;
    ushort4 h;
    h.x = f2bf(v0); h.y = f2bf(v1); h.z = f2bf(v2); h.w = f2bf(v3);
    *(ushort4*)(x16 + (size_t)i4 * 4) = h;
  }
}

// ---------------- pooling + head -------------------------------------------
__global__ void k_pool(const ushort_t* __restrict__ x16, const int* __restrict__ batch,
                       float* __restrict__ pool, int nRows) {
  int c = threadIdx.x;
  int rpb = (nRows + gridDim.x - 1) / gridDim.x;
  int r0 = blockIdx.x * rpb;
  int r1 = min(nRows, r0 + rpb);
  float acc = 0.f;
  int gc = -1;
  for (int r = r0; r < r1; ++r) {
    int g = batch[r];
    if (g != gc) {
      if (gc >= 0) atomicAdd(&pool[gc * 256 + c], acc);
      acc = 0.f;
      gc = g;
    }
    acc += bf2f(x16[(size_t)r * 256 + c]);
  }
  if (gc >= 0) atomicAdd(&pool[gc * 256 + c], acc);
}

// head with inline per-graph counts (batch sorted -> binary search)
__global__ void k_head(const float* __restrict__ pool, const int* __restrict__ batch,
                       const float* __restrict__ hW, const float* __restrict__ hb,
                       float* __restrict__ outp, int nRows) {
  int g = blockIdx.x, lane = threadIdx.x;
  int lo = 0, hi = nRows;
  while (lo < hi) { int mid = (lo + hi) >> 1; if (batch[mid] < g) lo = mid + 1; else hi = mid; }
  int lb = lo;
  lo = 0; hi = nRows;
  while (lo < hi) { int mid = (lo + hi) >> 1; if (batch[mid] < g + 1) lo = mid + 1; else hi = mid; }
  float cnt = fmaxf((float)(lo - lb), 1.0f);
  float z = 0.f;
#pragma unroll
  for (int i = 0; i < 4; ++i) {
    int c = lane + i * 64;
    float s = pool[g * 256 + c];
    z += (s / cnt) * hW[c] + s * hW[256 + c];
  }
#pragma unroll
  for (int off = 1; off < 64; off <<= 1) z += __shfl_xor(z, off, 64);
  if (lane == 0) outp[g] = z + hb[0];
}

// ---------------------------------------------------------------------------
extern "C" void kernel_launch(void* const* d_in, const int* in_sizes, int n_in,
                              void* d_out, int out_size, void* d_ws, size_t ws_size,
                              hipStream_t stream) {
  const float* node_features = (const float*)d_in[0];
  const int*   edge_index    = (const int*)d_in[1];
  const float* edge_attr     = (const float*)d_in[2];
  const int*   batch         = (const int*)d_in[3];
  const float* proj_W  = (const float*)d_in[4];
  const float* proj_b  = (const float*)d_in[5];
  const float* Wq      = (const float*)d_in[6];
  const float* bq      = (const float*)d_in[7];
  const float* Wk      = (const float*)d_in[8];
  const float* bk      = (const float*)d_in[9];
  const float* Wv      = (const float*)d_in[10];
  const float* bv      = (const float*)d_in[11];
  const float* We      = (const float*)d_in[12];
  const float* be      = (const float*)d_in[13];
  const float* Wskip   = (const float*)d_in[14];
  const float* bskip   = (const float*)d_in[15];
  const float* Wbeta   = (const float*)d_in[16];
  const float* bn_gamma= (const float*)d_in[17];
  const float* bn_beta = (const float*)d_in[18];
  const float* head_W  = (const float*)d_in[19];
  const float* head_b  = (const float*)d_in[20];
  float* out_dev = (float*)d_out;

  const int Nn = in_sizes[0] / 64;   // 50000
  const int Ee = in_sizes[1] / 2;    // 500000
  const int Gg = out_size;           // 64

  char* ws = (char*)d_ws;
  size_t off = 0;
  auto alloc = [&](size_t bytes) -> void* {
    void* p = ws + off;
    off += (bytes + 255) & ~(size_t)255;
    return p;
  };
  float*    Dqb    = (float*)alloc((size_t)Nn * 68 * 4);
  ushort_t* xb16   = (ushort_t*)alloc((size_t)Nn * 256 * 2);
  ushort_t* Qb16   = (ushort_t*)alloc((size_t)Nn * 256 * 2);
  ushort_t* Sb16   = (ushort_t*)alloc((size_t)Nn * 256 * 2);
  ushort_t* KVb    = (ushort_t*)alloc((size_t)Nn * 512 * 2);   // interleaved K|V
  ushort_t* Wcat_t = (ushort_t*)alloc((size_t)4 * 1152 * 256 * 2);
  float*    bias_cat = (float*)alloc((size_t)4 * 1152 * 4);
  float*    bnstat = (float*)alloc(512 * 4);
  float*    pool   = (float*)alloc((size_t)Gg * 256 * 4);
  int* deg     = (int*)alloc((size_t)Nn * 4);
  int* fill    = (int*)alloc((size_t)Nn * 4);
  int* row_ptr = (int*)alloc((size_t)(Nn + 1) * 4);
  int* csr     = (int*)alloc((size_t)Ee * 4);
  (void)ws_size; (void)n_in;

  const int* srcA = edge_index;
  const int* dstA = edge_index + Ee;

  // CSR build by dst
  hipMemsetAsync(deg, 0, (size_t)Nn * 4, stream);
  hipMemsetAsync(fill, 0, (size_t)Nn * 4, stream);
  k_count<<<(Ee + 255) / 256, 256, 0, stream>>>(dstA, deg, Ee);
  k_scan<<<1, 1024, 0, stream>>>(deg, row_ptr, Nn);
  k_scatter<<<(Ee + 255) / 256, 256, 0, stream>>>(dstA, row_ptr, fill, csr, Ee);

  // weight/bias conversion (bf16, transposed concat) + composite dq rows
  k_wconv<<<dim3(8, 8, 16), dim3(32, 8), 0, stream>>>(Wq, Wk, Wv, Wskip, Wcat_t);
  k_bconv<<<16, 256, 0, stream>>>(bq, bk, bv, bskip, bias_cat);
  k_mkdq<<<dim3(68, 4), 256, 0, stream>>>(Wq, bq, We, be, Wcat_t, bias_cat);

  // input projection (fp32 -> bf16)
  dim3 gemm_grid(256 / BN, (Nn + BM - 1) / BM);
  k_gemm<<<gemm_grid, 256, 0, stream>>>(node_features, proj_W, proj_b, xb16, Nn, 64, 256);

  int nodeBlocks = (Nn + 3) / 4;
  dim3 qkvs_grid(9, (Nn + 127) / 128);
  for (int l = 0; l < 4; ++l) {
    k_qkvs<<<qkvs_grid, 256, 0, stream>>>(xb16, Wcat_t + (size_t)l * (1152 * 256),
                                          bias_cat + l * 1152, Qb16, KVb, Sb16, Dqb, Nn);

    k_attn<<<nodeBlocks, 256, 0, stream>>>(Qb16, KVb, Dqb, edge_attr, srcA,
                                           We + (size_t)l * 4096, be + l * 256,
                                           Wbeta + (size_t)l * 768,
                                           row_ptr, csr, Sb16, xb16, Nn);

    hipMemsetAsync(bnstat, 0, 512 * 4, stream);
    k_bnstats<<<512, 256, 0, stream>>>(xb16, bnstat, bnstat + 256, Nn);
    k_bnapply<<<512, 256, 0, stream>>>(xb16, bnstat, bnstat + 256,
                                       bn_gamma + l * 256, bn_beta + l * 256, Nn);
  }

  hipMemsetAsync(pool, 0, (size_t)Gg * 256 * 4, stream);
  k_pool<<<256, 256, 0, stream>>>(xb16, batch, pool, Nn);
  k_head<<<Gg, 64, 0, stream>>>(pool, batch, head_W, head_b, out_dev, Nn);
}